// Round 2
// baseline (2651.902 us; speedup 1.0000x reference)
//
#include <hip/hip_runtime.h>
#include <math.h>

#define NS   1024
#define LP   27
#define MMH  34
#define EE   16
#define LO   21
#define CT   640
#define H1   512
#define H2   256
#define GSTR (LP*MMH)       // 918

// sinusoidal positional encoding value, matching numpy _pe()
__device__ __forceinline__ float pe_val(int pos, int e) {
    int j = e >> 1;
    float div = expf(-1.1512925464970229f * (float)j);  // 10000^(-j/8)
    float ang = (float)pos * div;
    return (e & 1) ? cosf(ang) : sinf(ang);
}

// ---------------- G[n,l,m] = sum_e pep_e[n,l,e] * mhc_e[n,m,e] ----------------
__global__ __launch_bounds__(128) void k_embG(
    const int* __restrict__ pep_x, const int* __restrict__ mhc_x,
    const float* __restrict__ emb_pep, const float* __restrict__ emb_mhc,
    float* __restrict__ G)
{
    int n = blockIdx.x, t = threadIdx.x;
    __shared__ float ps[LP * 17];
    __shared__ float ms[MMH * 17];
    for (int idx = t; idx < LP * EE; idx += 128) {
        int l = idx >> 4, e = idx & 15;
        float v = emb_pep[pep_x[n * LP + l] * EE + e];
        if (l >= 3 && l < 24) v += pe_val(l - 3, e);
        ps[l * 17 + e] = v;
    }
    for (int idx = t; idx < MMH * EE; idx += 128) {
        int m = idx >> 4, e = idx & 15;
        ms[m * 17 + e] = emb_mhc[mhc_x[n * MMH + m] * EE + e] + pe_val(m, e);
    }
    __syncthreads();
    for (int idx = t; idx < LP * MMH; idx += 128) {
        int l = idx / MMH, m = idx - l * MMH;
        float s = 0.f;
        #pragma unroll
        for (int e = 0; e < EE; ++e) s = fmaf(ps[l * 17 + e], ms[m * 17 + e], s);
        G[(size_t)n * GSTR + idx] = s;
    }
}

// ---------------- conv stage for one slot/chunk: Xc[r, C] with bn+relu ----------------
struct ConvArgs {
    const float* G;
    const float* w[3];
    const float* b[3];
    const float* g[3];
    const float* be[3];
    float* Xc;
    int n0;
    int rev;
};

__global__ __launch_bounds__(128) void k_conv(ConvArgs A) {
    const int KS_[3]  = {3, 5, 7};
    const int OFF_[3] = {2, 1, 0};
    const int C0_[3]  = {0, 128, 384};
    const int NC_[3]  = {128, 256, 256};
    int nloc = blockIdx.x;
    int n = A.n0 + nloc;
    int j = blockIdx.y;
    int K = KS_[j], off = OFF_[j], C0 = C0_[j], nc = NC_[j];
    const float* Gn = A.G + (size_t)n * GSTR;

    for (int c = threadIdx.x; c < nc; c += 128) {
        float acc[LO];
        #pragma unroll
        for (int i = 0; i < LO; ++i) acc[i] = 0.f;
        const float* Wc = A.w[j] + (size_t)c * K * MMH;
        for (int k = 0; k < K; ++k) {
            const float* gcol = Gn + (off + k) * MMH;
            const float* wrow = Wc + (size_t)(A.rev ? (K - 1 - k) : k) * MMH;
            for (int m = 0; m < MMH; ++m) {
                float wv = wrow[m];
                #pragma unroll
                for (int i = 0; i < LO; ++i)
                    acc[i] = fmaf(wv, gcol[i * MMH + m], acc[i]);
            }
        }
        float bv = A.b[j][c];
        float sc = A.g[j][c] / sqrtf(1.0f + 1e-5f);
        float bt = A.be[j][c];
        int Cg = C0 + c;
        for (int i = 0; i < LO; ++i) {
            float v = (acc[i] + bv) * sc + bt;
            v = fmaxf(v, 0.f);
            A.Xc[(size_t)(nloc * LO + i) * CT + Cg] = v;
        }
    }
}

// ---------------- tiled f32 GEMM with bn+relu epilogue ----------------
// out[p,o] = relu((sum_c Xin[p,c]*W[o,c] + b[o]) * g[o]/sqrt(1+eps) + be[o])
__global__ __launch_bounds__(256) void k_gemm(
    const float* __restrict__ Xin, int Cin,
    const float* __restrict__ W, const float* __restrict__ bb,
    const float* __restrict__ gg, const float* __restrict__ be,
    float* __restrict__ Yout, int Cout)
{
    __shared__ __align__(16) float As[16][132];
    __shared__ __align__(16) float Bs[16][132];
    int t  = threadIdx.x;
    int p0 = blockIdx.x * 128;
    int o0 = blockIdx.y * 128;

    int lr0 = t >> 2, lq = t & 3;
    int lr1 = lr0 + 64;
    int ty = t >> 4, tx = t & 15;

    float acc[8][8];
    #pragma unroll
    for (int u = 0; u < 8; ++u)
        #pragma unroll
        for (int v = 0; v < 8; ++v) acc[u][v] = 0.f;

    int nkt = Cin >> 4;
    for (int kt = 0; kt < nkt; ++kt) {
        int k0 = kt << 4;
        float4 a0 = *(const float4*)&Xin[(size_t)(p0 + lr0) * Cin + k0 + lq * 4];
        float4 a1 = *(const float4*)&Xin[(size_t)(p0 + lr1) * Cin + k0 + lq * 4];
        float4 b0 = *(const float4*)&W[(size_t)(o0 + lr0) * Cin + k0 + lq * 4];
        float4 b1 = *(const float4*)&W[(size_t)(o0 + lr1) * Cin + k0 + lq * 4];
        __syncthreads();
        As[lq * 4 + 0][lr0] = a0.x; As[lq * 4 + 1][lr0] = a0.y;
        As[lq * 4 + 2][lr0] = a0.z; As[lq * 4 + 3][lr0] = a0.w;
        As[lq * 4 + 0][lr1] = a1.x; As[lq * 4 + 1][lr1] = a1.y;
        As[lq * 4 + 2][lr1] = a1.z; As[lq * 4 + 3][lr1] = a1.w;
        Bs[lq * 4 + 0][lr0] = b0.x; Bs[lq * 4 + 1][lr0] = b0.y;
        Bs[lq * 4 + 2][lr0] = b0.z; Bs[lq * 4 + 3][lr0] = b0.w;
        Bs[lq * 4 + 0][lr1] = b1.x; Bs[lq * 4 + 1][lr1] = b1.y;
        Bs[lq * 4 + 2][lr1] = b1.z; Bs[lq * 4 + 3][lr1] = b1.w;
        __syncthreads();
        #pragma unroll
        for (int kk = 0; kk < 16; ++kk) {
            float a_[8], b_[8];
            *(float4*)&a_[0] = *(const float4*)&As[kk][ty * 8];
            *(float4*)&a_[4] = *(const float4*)&As[kk][ty * 8 + 4];
            *(float4*)&b_[0] = *(const float4*)&Bs[kk][tx * 8];
            *(float4*)&b_[4] = *(const float4*)&Bs[kk][tx * 8 + 4];
            #pragma unroll
            for (int u = 0; u < 8; ++u)
                #pragma unroll
                for (int v = 0; v < 8; ++v)
                    acc[u][v] = fmaf(a_[u], b_[v], acc[u][v]);
        }
    }

    float bcol[8], scol[8], becol[8];
    #pragma unroll
    for (int v = 0; v < 8; ++v) {
        int cidx = o0 + tx * 8 + v;
        bcol[v]  = bb[cidx];
        scol[v]  = gg[cidx] / sqrtf(1.0f + 1e-5f);
        becol[v] = be[cidx];
    }
    #pragma unroll
    for (int u = 0; u < 8; ++u) {
        int p = p0 + ty * 8 + u;
        float o_[8];
        #pragma unroll
        for (int v = 0; v < 8; ++v) {
            float val = (acc[u][v] + bcol[v]) * scol[v] + becol[v];
            o_[v] = fmaxf(val, 0.f);
        }
        *(float4*)&Yout[(size_t)p * Cout + o0 + tx * 8]     = *(const float4*)&o_[0];
        *(float4*)&Yout[(size_t)p * Cout + o0 + tx * 8 + 4] = *(const float4*)&o_[4];
    }
}

// ---------------- masked max-pool over i for one slot/chunk ----------------
__global__ __launch_bounds__(128) void k_pool(
    const float* __restrict__ Zc, const int* __restrict__ pep_x,
    float* __restrict__ pool, int n0, int slot)
{
    int nloc = blockIdx.x;
    int n = n0 + nloc;
    int c = blockIdx.y * 128 + threadIdx.x;
    float m = -INFINITY;
    for (int i = 0; i < LO; ++i)
        if (pep_x[n * LP + 3 + i] != 0)
            m = fmaxf(m, Zc[(size_t)(nloc * LO + i) * H2 + c]);
    pool[(size_t)n * (3 * H2) + slot * H2 + c] = m;
}

// ---------------- attention head per sample ----------------
__global__ __launch_bounds__(256) void k_poolhead(
    const float* __restrict__ pool,
    const float* __restrict__ w_att1, const float* __restrict__ b_att1,
    const float* __restrict__ w_att2, const float* __restrict__ b_att2,
    const float* __restrict__ w_out, const float* __restrict__ b_out,
    float* __restrict__ a_out, float* __restrict__ s2_out)
{
    int n = blockIdx.x, c = threadIdx.x;
    __shared__ float feat_s[H2];
    __shared__ float red[7][H2];
    __shared__ float sc_s[6];

    float mx[3];
    #pragma unroll
    for (int w = 0; w < 3; ++w)
        mx[w] = pool[(size_t)n * (3 * H2) + w * H2 + c];

    float fv = (mx[0] + mx[1] + mx[2]) * (1.f / 3.f);
    feat_s[c] = fv;
    #pragma unroll
    for (int o = 0; o < 2; ++o)
        #pragma unroll
        for (int w = 0; w < 3; ++w)
            red[o * 3 + w][c] = w_out[o * H2 + c] * mx[w];
    __syncthreads();

    float hacc = 0.f;
    for (int cc = 0; cc < H2; ++cc)
        hacc = fmaf(w_att1[(size_t)c * H2 + cc], feat_s[cc], hacc);
    float h = tanhf(hacc + b_att1[c]);
    red[6][c] = h * w_att2[c];
    __syncthreads();

    for (int s = 128; s > 0; s >>= 1) {
        if (c < s) {
            #pragma unroll
            for (int jj = 0; jj < 7; ++jj) red[jj][c] += red[jj][c + s];
        }
        __syncthreads();
    }
    if (c == 0) a_out[n] = red[6][0] + b_att2[0];
    if (c < 6) {
        float x = red[c][0] + b_out[c / 3];
        sc_s[c] = 1.f / (1.f + expf(-x));
    }
    __syncthreads();
    if (c < 2) {
        float half = 0.5f * (sc_s[c * 3 + 0] + sc_s[c * 3 + 1]);
        s2_out[n * 2 + c] = fmaxf(half, sc_s[c * 3 + 2]);   // inverse==1 path
    }
}

// ---------------- bag segment softmax + weighted sum ----------------
__global__ __launch_bounds__(1024) void k_final(
    const float* __restrict__ a_in, const float* __restrict__ s2_in,
    const int* __restrict__ bags, float* __restrict__ out)
{
    __shared__ float a_s[NS], s0_s[NS], s1_s[NS];
    __shared__ int off_s[33];
    int t = threadIdx.x;
    a_s[t]  = a_in[t];
    s0_s[t] = s2_in[t * 2 + 0];
    s1_s[t] = s2_in[t * 2 + 1];
    if (t == 0) {
        off_s[0] = 0;
        for (int g = 0; g < 32; ++g) off_s[g + 1] = off_s[g] + bags[g];
    }
    __syncthreads();
    if (t < 32) {
        int st = off_s[t], en = off_s[t + 1];
        float mxv = -INFINITY;
        for (int n = st; n < en; ++n) mxv = fmaxf(mxv, a_s[n]);
        float se = 0.f;
        for (int n = st; n < en; ++n) se += expf(a_s[n] - mxv);
        float inv = 1.f / se;
        float o0 = 0.f, o1 = 0.f;
        for (int n = st; n < en; ++n) {
            float w = expf(a_s[n] - mxv) * inv;
            o0 += w * s0_s[n];
            o1 += w * s1_s[n];
        }
        out[t * 2 + 0] = fminf(fmaxf(o0, 0.f), 1.f);
        out[t * 2 + 1] = fminf(fmaxf(o1, 0.f), 1.f);
    }
}

extern "C" void kernel_launch(void* const* d_in, const int* in_sizes, int n_in,
                              void* d_out, int out_size, void* d_ws, size_t ws_size,
                              hipStream_t stream) {
    const int* pep_x = (const int*)d_in[0];
    const int* mhc_x = (const int*)d_in[1];
    const int* bags  = (const int*)d_in[4];
    const float* emb_pep = (const float*)d_in[6];
    const float* emb_mhc = (const float*)d_in[7];

    float* ws = (float*)d_ws;
    size_t ws_floats = ws_size / 4;

    // choose chunk size (samples per chunk) to fit ws_size; Cn*21 must be /128
    int Cn = 1024;
    while (Cn > 128) {
        size_t need = 786432ull + 1024 + 2048 + 940032ull
                    + (size_t)Cn * LO * (CT + H1);
        if (need <= ws_floats) break;
        Cn >>= 1;
    }
    int R = Cn * LO;

    // workspace layout (float offsets)
    float* pool   = ws;                     // 1024*3*256 = 786432
    float* a_buf  = ws + 786432;            // 1024
    float* s2_buf = ws + 787456;            // 2048
    float* G      = ws + 789504;            // 1024*918 = 940032
    float* Xc     = ws + 1729536;           // R*640
    float* Yc     = Xc + (size_t)R * CT;    // R*512
    float* Zc     = Xc;                     // R*256 aliases dead Xc

    k_embG<<<dim3(NS), dim3(128), 0, stream>>>(pep_x, mhc_x, emb_pep, emb_mhc, G);

    for (int slot = 0; slot < 3; ++slot) {
        int fr  = (slot == 0) ? 0 : 1;      // conv weight family: f or r
        int rev = (slot == 2) ? 1 : 0;      // k-reversed weights for slot 2
        int cbase = fr ? 20 : 8;            // w_cf* at 8.., w_cr* at 20..
        int lbase = fr ? 40 : 32;           // lins_f at 32.., lins_r at 40..

        ConvArgs ca;
        ca.G = G; ca.Xc = Xc; ca.rev = rev;
        for (int j = 0; j < 3; ++j) {
            ca.w[j]  = (const float*)d_in[cbase + 4 * j + 0];
            ca.b[j]  = (const float*)d_in[cbase + 4 * j + 1];
            ca.g[j]  = (const float*)d_in[cbase + 4 * j + 2];
            ca.be[j] = (const float*)d_in[cbase + 4 * j + 3];
        }

        const float* wA  = (const float*)d_in[lbase + 0];
        const float* bA  = (const float*)d_in[lbase + 1];
        const float* gA  = (const float*)d_in[lbase + 2];
        const float* beA = (const float*)d_in[lbase + 3];
        const float* wB  = (const float*)d_in[lbase + 4];
        const float* bB  = (const float*)d_in[lbase + 5];
        const float* gB  = (const float*)d_in[lbase + 6];
        const float* beB = (const float*)d_in[lbase + 7];

        for (int n0 = 0; n0 < NS; n0 += Cn) {
            ca.n0 = n0;
            k_conv<<<dim3(Cn, 3), dim3(128), 0, stream>>>(ca);
            k_gemm<<<dim3(R / 128, H1 / 128), dim3(256), 0, stream>>>(
                Xc, CT, wA, bA, gA, beA, Yc, H1);
            k_gemm<<<dim3(R / 128, H2 / 128), dim3(256), 0, stream>>>(
                Yc, H1, wB, bB, gB, beB, Zc, H2);
            k_pool<<<dim3(Cn, H2 / 128), dim3(128), 0, stream>>>(
                Zc, pep_x, pool, n0, slot);
        }
    }

    k_poolhead<<<dim3(NS), dim3(256), 0, stream>>>(
        pool,
        (const float*)d_in[48], (const float*)d_in[49], (const float*)d_in[50], (const float*)d_in[51],
        (const float*)d_in[52], (const float*)d_in[53],
        a_buf, s2_buf);

    k_final<<<dim3(1), dim3(1024), 0, stream>>>(a_buf, s2_buf, bags, (float*)d_out);
}

// Round 4
// 1323.682 us; speedup vs baseline: 2.0034x; 2.0034x over previous
//
#include <hip/hip_runtime.h>
#include <math.h>

#define NS   1024
#define LP   27
#define MMH  34
#define EE   16
#define LO   21
#define CT   640
#define H1   512
#define H2   256
#define GSTR (LP*MMH)       // 918

// packed conv-weight geometry (K padded to mult of 16 in "k*34+m" units)
// j:      0         1         2
// K:      3         5         7
// K*34:   102       170       238
// Kc:     112       176       240
// nc:     128       256       256
// C0:     0         128       384
__constant__ const int KS_c[3]  = {3, 5, 7};
__constant__ const int OFF_c[3] = {2, 1, 0};
__constant__ const int KC_c[3]  = {112, 176, 240};
__constant__ const int NC_c[3]  = {128, 256, 256};
__constant__ const int C0_c[3]  = {0, 128, 384};
// per-slot packed offsets
#define PK_SLOT 120832              // 128*112 + 256*176 + 256*240
#define PK_J0   0
#define PK_J1   14336               // 128*112
#define PK_J2   59392               // + 256*176
#define BP_SLOT 640
#define BP_J0   0
#define BP_J1   128
#define BP_J2   384

// sinusoidal positional encoding value, matching numpy _pe()
__device__ __forceinline__ float pe_val(int pos, int e) {
    int j = e >> 1;
    float div = expf(-1.1512925464970229f * (float)j);  // 10000^(-j/8)
    float ang = (float)pos * div;
    return (e & 1) ? cosf(ang) : sinf(ang);
}

// ---------------- G[n,l,m] = sum_e pep_e[n,l,e] * mhc_e[n,m,e] ----------------
__global__ __launch_bounds__(128) void k_embG(
    const int* __restrict__ pep_x, const int* __restrict__ mhc_x,
    const float* __restrict__ emb_pep, const float* __restrict__ emb_mhc,
    float* __restrict__ G)
{
    int n = blockIdx.x, t = threadIdx.x;
    __shared__ float ps[LP * 17];
    __shared__ float ms[MMH * 17];
    for (int idx = t; idx < LP * EE; idx += 128) {
        int l = idx >> 4, e = idx & 15;
        float v = emb_pep[pep_x[n * LP + l] * EE + e];
        if (l >= 3 && l < 24) v += pe_val(l - 3, e);
        ps[l * 17 + e] = v;
    }
    for (int idx = t; idx < MMH * EE; idx += 128) {
        int m = idx >> 4, e = idx & 15;
        ms[m * 17 + e] = emb_mhc[mhc_x[n * MMH + m] * EE + e] + pe_val(m, e);
    }
    __syncthreads();
    for (int idx = t; idx < LP * MMH; idx += 128) {
        int l = idx / MMH, m = idx - l * MMH;
        float s = 0.f;
        #pragma unroll
        for (int e = 0; e < EE; ++e) s = fmaf(ps[l * 17 + e], ms[m * 17 + e], s);
        G[(size_t)n * GSTR + idx] = s;
    }
}

// ---------------- pack conv weights: fold BN scale, zero-pad K, slot-2 k-reversal ----------------
struct PackArgs {
    const float* w[2][3];
    const float* b[2][3];
    const float* g[2][3];
    const float* be[2][3];
    float* Wp;
    float* bp;
};

__global__ __launch_bounds__(256) void k_pack(PackArgs A) {
    int s = blockIdx.x, j = blockIdx.y, t = threadIdx.x;
    int K = KS_c[j], Kc = KC_c[j], nc = NC_c[j];
    int fam = (s == 0) ? 0 : 1;
    const float* w  = A.w[fam][j];
    const float* b  = A.b[fam][j];
    const float* g  = A.g[fam][j];
    const float* be = A.be[fam][j];
    const int pkoff[3] = {PK_J0, PK_J1, PK_J2};
    const int bpoff[3] = {BP_J0, BP_J1, BP_J2};
    float* Wp = A.Wp + s * PK_SLOT + pkoff[j];
    float* bp = A.bp + s * BP_SLOT + bpoff[j];
    float rs = rsqrtf(1.0f + 1e-5f);
    int tot = nc * Kc;
    for (int idx = t; idx < tot; idx += 256) {
        int c = idx / Kc, col = idx - c * Kc;
        float v = 0.f;
        if (col < K * MMH) {
            int k = col / MMH, m = col - k * MMH;
            int kk = (s == 2) ? (K - 1 - k) : k;
            v = w[((size_t)c * K + kk) * MMH + m] * (g[c] * rs);
        }
        Wp[idx] = v;
    }
    for (int c = t; c < nc; c += 256)
        bp[c] = b[c] * (g[c] * rs) + be[c];
}

// ---------------- conv as GEMM over windowed-G rows ----------------
// out[p, o] = relu( sum_col G[n(p)*918 + (off+i(p))*34 + col] * Wp[o*Kc + col] + bp[o] )
__global__ __launch_bounds__(256) void k_cgemm(
    const float* __restrict__ G, int n0, int off, int nkt, int Kc,
    const float* __restrict__ Wp, const float* __restrict__ bp,
    float* __restrict__ Xc, int C0)
{
    __shared__ __align__(16) float As[16][132];
    __shared__ __align__(16) float Bs[16][132];
    int t  = threadIdx.x;
    int p0 = blockIdx.x * 128;
    int o0 = blockIdx.y * 128;

    int lr0 = t >> 2, lq = t & 3;
    int lr1 = lr0 + 64;
    int ty = t >> 4, tx = t & 15;

    // row -> G window base (hoisted; contiguous slice per row)
    int pl0 = p0 + lr0, pl1 = p0 + lr1;
    int nA0 = n0 + pl0 / LO, iA0 = pl0 % LO;
    int nA1 = n0 + pl1 / LO, iA1 = pl1 % LO;
    size_t ab0 = (size_t)nA0 * GSTR + (off + iA0) * MMH;
    size_t ab1 = (size_t)nA1 * GSTR + (off + iA1) * MMH;

    float acc[8][8];
    #pragma unroll
    for (int u = 0; u < 8; ++u)
        #pragma unroll
        for (int v = 0; v < 8; ++v) acc[u][v] = 0.f;

    for (int kt = 0; kt < nkt; ++kt) {
        int k0 = kt << 4;
        // A: 8B-aligned windows -> float2 loads
        float2 a0lo = *(const float2*)&G[ab0 + k0 + lq * 4];
        float2 a0hi = *(const float2*)&G[ab0 + k0 + lq * 4 + 2];
        float2 a1lo = *(const float2*)&G[ab1 + k0 + lq * 4];
        float2 a1hi = *(const float2*)&G[ab1 + k0 + lq * 4 + 2];
        float4 b0 = *(const float4*)&Wp[(size_t)(o0 + lr0) * Kc + k0 + lq * 4];
        float4 b1 = *(const float4*)&Wp[(size_t)(o0 + lr1) * Kc + k0 + lq * 4];
        __syncthreads();
        As[lq * 4 + 0][lr0] = a0lo.x; As[lq * 4 + 1][lr0] = a0lo.y;
        As[lq * 4 + 2][lr0] = a0hi.x; As[lq * 4 + 3][lr0] = a0hi.y;
        As[lq * 4 + 0][lr1] = a1lo.x; As[lq * 4 + 1][lr1] = a1lo.y;
        As[lq * 4 + 2][lr1] = a1hi.x; As[lq * 4 + 3][lr1] = a1hi.y;
        Bs[lq * 4 + 0][lr0] = b0.x; Bs[lq * 4 + 1][lr0] = b0.y;
        Bs[lq * 4 + 2][lr0] = b0.z; Bs[lq * 4 + 3][lr0] = b0.w;
        Bs[lq * 4 + 0][lr1] = b1.x; Bs[lq * 4 + 1][lr1] = b1.y;
        Bs[lq * 4 + 2][lr1] = b1.z; Bs[lq * 4 + 3][lr1] = b1.w;
        __syncthreads();
        #pragma unroll
        for (int kk = 0; kk < 16; ++kk) {
            float a_[8], b_[8];
            *(float4*)&a_[0] = *(const float4*)&As[kk][ty * 8];
            *(float4*)&a_[4] = *(const float4*)&As[kk][ty * 8 + 4];
            *(float4*)&b_[0] = *(const float4*)&Bs[kk][tx * 8];
            *(float4*)&b_[4] = *(const float4*)&Bs[kk][tx * 8 + 4];
            #pragma unroll
            for (int u = 0; u < 8; ++u)
                #pragma unroll
                for (int v = 0; v < 8; ++v)
                    acc[u][v] = fmaf(a_[u], b_[v], acc[u][v]);
        }
    }

    float bcol[8];
    #pragma unroll
    for (int v = 0; v < 8; ++v) bcol[v] = bp[o0 + tx * 8 + v];
    #pragma unroll
    for (int u = 0; u < 8; ++u) {
        int p = p0 + ty * 8 + u;
        float o_[8];
        #pragma unroll
        for (int v = 0; v < 8; ++v)
            o_[v] = fmaxf(acc[u][v] + bcol[v], 0.f);
        float* dst = &Xc[(size_t)p * CT + C0 + o0 + tx * 8];
        *(float4*)&dst[0] = *(const float4*)&o_[0];
        *(float4*)&dst[4] = *(const float4*)&o_[4];
    }
}

// ---------------- tiled f32 GEMM with bn+relu epilogue ----------------
__global__ __launch_bounds__(256) void k_gemm(
    const float* __restrict__ Xin, int Cin,
    const float* __restrict__ W, const float* __restrict__ bb,
    const float* __restrict__ gg, const float* __restrict__ be,
    float* __restrict__ Yout, int Cout)
{
    __shared__ __align__(16) float As[16][132];
    __shared__ __align__(16) float Bs[16][132];
    int t  = threadIdx.x;
    int p0 = blockIdx.x * 128;
    int o0 = blockIdx.y * 128;

    int lr0 = t >> 2, lq = t & 3;
    int lr1 = lr0 + 64;
    int ty = t >> 4, tx = t & 15;

    float acc[8][8];
    #pragma unroll
    for (int u = 0; u < 8; ++u)
        #pragma unroll
        for (int v = 0; v < 8; ++v) acc[u][v] = 0.f;

    int nkt = Cin >> 4;
    for (int kt = 0; kt < nkt; ++kt) {
        int k0 = kt << 4;
        float4 a0 = *(const float4*)&Xin[(size_t)(p0 + lr0) * Cin + k0 + lq * 4];
        float4 a1 = *(const float4*)&Xin[(size_t)(p0 + lr1) * Cin + k0 + lq * 4];
        float4 b0 = *(const float4*)&W[(size_t)(o0 + lr0) * Cin + k0 + lq * 4];
        float4 b1 = *(const float4*)&W[(size_t)(o0 + lr1) * Cin + k0 + lq * 4];
        __syncthreads();
        As[lq * 4 + 0][lr0] = a0.x; As[lq * 4 + 1][lr0] = a0.y;
        As[lq * 4 + 2][lr0] = a0.z; As[lq * 4 + 3][lr0] = a0.w;
        As[lq * 4 + 0][lr1] = a1.x; As[lq * 4 + 1][lr1] = a1.y;
        As[lq * 4 + 2][lr1] = a1.z; As[lq * 4 + 3][lr1] = a1.w;
        Bs[lq * 4 + 0][lr0] = b0.x; Bs[lq * 4 + 1][lr0] = b0.y;
        Bs[lq * 4 + 2][lr0] = b0.z; Bs[lq * 4 + 3][lr0] = b0.w;
        Bs[lq * 4 + 0][lr1] = b1.x; Bs[lq * 4 + 1][lr1] = b1.y;
        Bs[lq * 4 + 2][lr1] = b1.z; Bs[lq * 4 + 3][lr1] = b1.w;
        __syncthreads();
        #pragma unroll
        for (int kk = 0; kk < 16; ++kk) {
            float a_[8], b_[8];
            *(float4*)&a_[0] = *(const float4*)&As[kk][ty * 8];
            *(float4*)&a_[4] = *(const float4*)&As[kk][ty * 8 + 4];
            *(float4*)&b_[0] = *(const float4*)&Bs[kk][tx * 8];
            *(float4*)&b_[4] = *(const float4*)&Bs[kk][tx * 8 + 4];
            #pragma unroll
            for (int u = 0; u < 8; ++u)
                #pragma unroll
                for (int v = 0; v < 8; ++v)
                    acc[u][v] = fmaf(a_[u], b_[v], acc[u][v]);
        }
    }

    float bcol[8], scol[8], becol[8];
    #pragma unroll
    for (int v = 0; v < 8; ++v) {
        int cidx = o0 + tx * 8 + v;
        bcol[v]  = bb[cidx];
        scol[v]  = gg[cidx] / sqrtf(1.0f + 1e-5f);
        becol[v] = be[cidx];
    }
    #pragma unroll
    for (int u = 0; u < 8; ++u) {
        int p = p0 + ty * 8 + u;
        float o_[8];
        #pragma unroll
        for (int v = 0; v < 8; ++v) {
            float val = (acc[u][v] + bcol[v]) * scol[v] + becol[v];
            o_[v] = fmaxf(val, 0.f);
        }
        *(float4*)&Yout[(size_t)p * Cout + o0 + tx * 8]     = *(const float4*)&o_[0];
        *(float4*)&Yout[(size_t)p * Cout + o0 + tx * 8 + 4] = *(const float4*)&o_[4];
    }
}

// ---------------- masked max-pool over i for one slot/chunk ----------------
__global__ __launch_bounds__(128) void k_pool(
    const float* __restrict__ Zc, const int* __restrict__ pep_x,
    float* __restrict__ pool, int n0, int slot)
{
    int nloc = blockIdx.x;
    int n = n0 + nloc;
    int c = blockIdx.y * 128 + threadIdx.x;
    float m = -INFINITY;
    for (int i = 0; i < LO; ++i)
        if (pep_x[n * LP + 3 + i] != 0)
            m = fmaxf(m, Zc[(size_t)(nloc * LO + i) * H2 + c]);
    pool[(size_t)n * (3 * H2) + slot * H2 + c] = m;
}

// ---------------- attention head per sample ----------------
__global__ __launch_bounds__(256) void k_poolhead(
    const float* __restrict__ pool,
    const float* __restrict__ w_att1, const float* __restrict__ b_att1,
    const float* __restrict__ w_att2, const float* __restrict__ b_att2,
    const float* __restrict__ w_out, const float* __restrict__ b_out,
    float* __restrict__ a_out, float* __restrict__ s2_out)
{
    int n = blockIdx.x, c = threadIdx.x;
    __shared__ float feat_s[H2];
    __shared__ float red[7][H2];
    __shared__ float sc_s[6];

    float mx[3];
    #pragma unroll
    for (int w = 0; w < 3; ++w)
        mx[w] = pool[(size_t)n * (3 * H2) + w * H2 + c];

    float fv = (mx[0] + mx[1] + mx[2]) * (1.f / 3.f);
    feat_s[c] = fv;
    #pragma unroll
    for (int o = 0; o < 2; ++o)
        #pragma unroll
        for (int w = 0; w < 3; ++w)
            red[o * 3 + w][c] = w_out[o * H2 + c] * mx[w];
    __syncthreads();

    float hacc = 0.f;
    for (int cc = 0; cc < H2; ++cc)
        hacc = fmaf(w_att1[(size_t)c * H2 + cc], feat_s[cc], hacc);
    float h = tanhf(hacc + b_att1[c]);
    red[6][c] = h * w_att2[c];
    __syncthreads();

    for (int s = 128; s > 0; s >>= 1) {
        if (c < s) {
            #pragma unroll
            for (int jj = 0; jj < 7; ++jj) red[jj][c] += red[jj][c + s];
        }
        __syncthreads();
    }
    if (c == 0) a_out[n] = red[6][0] + b_att2[0];
    if (c < 6) {
        float x = red[c][0] + b_out[c / 3];
        sc_s[c] = 1.f / (1.f + expf(-x));
    }
    __syncthreads();
    if (c < 2) {
        float half = 0.5f * (sc_s[c * 3 + 0] + sc_s[c * 3 + 1]);
        s2_out[n * 2 + c] = fmaxf(half, sc_s[c * 3 + 2]);   // inverse==1 path
    }
}

// ---------------- bag segment softmax + weighted sum ----------------
__global__ __launch_bounds__(1024) void k_final(
    const float* __restrict__ a_in, const float* __restrict__ s2_in,
    const int* __restrict__ bags, float* __restrict__ out)
{
    __shared__ float a_s[NS], s0_s[NS], s1_s[NS];
    __shared__ int off_s[33];
    int t = threadIdx.x;
    a_s[t]  = a_in[t];
    s0_s[t] = s2_in[t * 2 + 0];
    s1_s[t] = s2_in[t * 2 + 1];
    if (t == 0) {
        off_s[0] = 0;
        for (int g = 0; g < 32; ++g) off_s[g + 1] = off_s[g] + bags[g];
    }
    __syncthreads();
    if (t < 32) {
        int st = off_s[t], en = off_s[t + 1];
        float mxv = -INFINITY;
        for (int n = st; n < en; ++n) mxv = fmaxf(mxv, a_s[n]);
        float se = 0.f;
        for (int n = st; n < en; ++n) se += expf(a_s[n] - mxv);
        float inv = 1.f / se;
        float o0 = 0.f, o1 = 0.f;
        for (int n = st; n < en; ++n) {
            float w = expf(a_s[n] - mxv) * inv;
            o0 += w * s0_s[n];
            o1 += w * s1_s[n];
        }
        out[t * 2 + 0] = fminf(fmaxf(o0, 0.f), 1.f);
        out[t * 2 + 1] = fminf(fmaxf(o1, 0.f), 1.f);
    }
}

extern "C" void kernel_launch(void* const* d_in, const int* in_sizes, int n_in,
                              void* d_out, int out_size, void* d_ws, size_t ws_size,
                              hipStream_t stream) {
    const int* pep_x = (const int*)d_in[0];
    const int* mhc_x = (const int*)d_in[1];
    const int* bags  = (const int*)d_in[4];
    const float* emb_pep = (const float*)d_in[6];
    const float* emb_mhc = (const float*)d_in[7];

    float* ws = (float*)d_ws;
    size_t ws_floats = ws_size / 4;

    // workspace layout (float offsets)
    const size_t POOL_OFF  = 0;           // 786432
    const size_t A_OFF     = 786432;      // 1024
    const size_t S2_OFF    = 787456;      // 2048
    const size_t WP_OFF    = 789504;      // 362496 packed conv weights
    const size_t BP_OFF    = 1152000;     // 1920   packed conv bias
    const size_t G_OFF     = 1155072;     // 940032 + 64 slack (j=2 window overread)
    const size_t XC_OFF    = 2095168;

    float* pool   = ws + POOL_OFF;
    float* a_buf  = ws + A_OFF;
    float* s2_buf = ws + S2_OFF;
    float* Wpack  = ws + WP_OFF;
    float* bpack  = ws + BP_OFF;
    float* G      = ws + G_OFF;

    // choose chunk size (samples per chunk) to fit ws_size
    int Cn = 1024;
    while (Cn > 128) {
        size_t need = XC_OFF + (size_t)Cn * LO * (CT + H1);
        if (need <= ws_floats) break;
        Cn >>= 1;
    }
    int R = Cn * LO;
    float* Xc = ws + XC_OFF;              // R*640
    float* Yc = Xc + (size_t)R * CT;      // R*512
    float* Zc = Xc;                       // R*256 aliases dead Xc

    k_embG<<<dim3(NS), dim3(128), 0, stream>>>(pep_x, mhc_x, emb_pep, emb_mhc, G);

    PackArgs pa;
    for (int j = 0; j < 3; ++j) {
        pa.w[0][j]  = (const float*)d_in[8 + 4 * j];
        pa.b[0][j]  = (const float*)d_in[9 + 4 * j];
        pa.g[0][j]  = (const float*)d_in[10 + 4 * j];
        pa.be[0][j] = (const float*)d_in[11 + 4 * j];
        pa.w[1][j]  = (const float*)d_in[20 + 4 * j];
        pa.b[1][j]  = (const float*)d_in[21 + 4 * j];
        pa.g[1][j]  = (const float*)d_in[22 + 4 * j];
        pa.be[1][j] = (const float*)d_in[23 + 4 * j];
    }
    pa.Wp = Wpack; pa.bp = bpack;
    k_pack<<<dim3(3, 3), dim3(256), 0, stream>>>(pa);

    const int pkoff[3] = {PK_J0, PK_J1, PK_J2};
    const int bpoff[3] = {BP_J0, BP_J1, BP_J2};
    const int KC_[3]   = {112, 176, 240};
    const int OFF_[3]  = {2, 1, 0};
    const int NC_[3]   = {128, 256, 256};
    const int C0_[3]   = {0, 128, 384};

    for (int slot = 0; slot < 3; ++slot) {
        int fr = (slot == 0) ? 0 : 1;
        int lbase = fr ? 40 : 32;          // lins_f at 32.., lins_r at 40..
        const float* wA  = (const float*)d_in[lbase + 0];
        const float* bA  = (const float*)d_in[lbase + 1];
        const float* gA  = (const float*)d_in[lbase + 2];
        const float* beA = (const float*)d_in[lbase + 3];
        const float* wB  = (const float*)d_in[lbase + 4];
        const float* bB  = (const float*)d_in[lbase + 5];
        const float* gB  = (const float*)d_in[lbase + 6];
        const float* beB = (const float*)d_in[lbase + 7];

        for (int n0 = 0; n0 < NS; n0 += Cn) {
            for (int j = 0; j < 3; ++j) {
                k_cgemm<<<dim3(R / 128, NC_[j] / 128), dim3(256), 0, stream>>>(
                    G, n0, OFF_[j], KC_[j] / 16, KC_[j],
                    Wpack + slot * PK_SLOT + pkoff[j],
                    bpack + slot * BP_SLOT + bpoff[j],
                    Xc, C0_[j]);
            }
            k_gemm<<<dim3(R / 128, H1 / 128), dim3(256), 0, stream>>>(
                Xc, CT, wA, bA, gA, beA, Yc, H1);
            k_gemm<<<dim3(R / 128, H2 / 128), dim3(256), 0, stream>>>(
                Yc, H1, wB, bB, gB, beB, Zc, H2);
            k_pool<<<dim3(Cn, H2 / 128), dim3(128), 0, stream>>>(
                Zc, pep_x, pool, n0, slot);
        }
    }

    k_poolhead<<<dim3(NS), dim3(256), 0, stream>>>(
        pool,
        (const float*)d_in[48], (const float*)d_in[49], (const float*)d_in[50], (const float*)d_in[51],
        (const float*)d_in[52], (const float*)d_in[53],
        a_buf, s2_buf);

    k_final<<<dim3(1), dim3(1024), 0, stream>>>(a_buf, s2_buf, bags, (float*)d_out);
}

// Round 5
// 622.217 us; speedup vs baseline: 4.2620x; 2.1274x over previous
//
#include <hip/hip_runtime.h>
#include <hip/hip_bf16.h>
#include <math.h>

#define NS   1024
#define LP   27
#define MMH  34
#define EE   16
#define LO   21
#define CT   640
#define H1   512
#define H2   256
#define GSTR (LP*MMH)       // 918

typedef __attribute__((ext_vector_type(8))) short  s8v;
typedef __attribute__((ext_vector_type(4))) float  f4v;

// packed conv-weight geometry (K padded to mult of 16 in "k*34+m" units)
__constant__ const int KS_c[3]  = {3, 5, 7};
__constant__ const int KC_c[3]  = {112, 176, 240};
__constant__ const int NC_c[3]  = {128, 256, 256};
// per-slot packed offsets
#define PK_SLOT 120832              // 128*112 + 256*176 + 256*240
#define PK_J0   0
#define PK_J1   14336               // 128*112
#define PK_J2   59392               // + 256*176
#define BP_SLOT 640
#define BP_J0   0
#define BP_J1   128
#define BP_J2   384

// sinusoidal positional encoding value, matching numpy _pe()
__device__ __forceinline__ float pe_val(int pos, int e) {
    int j = e >> 1;
    float div = expf(-1.1512925464970229f * (float)j);  // 10000^(-j/8)
    float ang = (float)pos * div;
    return (e & 1) ? cosf(ang) : sinf(ang);
}

// ---------------- G[n,l,m] = sum_e pep_e[n,l,e] * mhc_e[n,m,e] ----------------
__global__ __launch_bounds__(128) void k_embG(
    const int* __restrict__ pep_x, const int* __restrict__ mhc_x,
    const float* __restrict__ emb_pep, const float* __restrict__ emb_mhc,
    float* __restrict__ G)
{
    int n = blockIdx.x, t = threadIdx.x;
    __shared__ float ps[LP * 17];
    __shared__ float ms[MMH * 17];
    for (int idx = t; idx < LP * EE; idx += 128) {
        int l = idx >> 4, e = idx & 15;
        float v = emb_pep[pep_x[n * LP + l] * EE + e];
        if (l >= 3 && l < 24) v += pe_val(l - 3, e);
        ps[l * 17 + e] = v;
    }
    for (int idx = t; idx < MMH * EE; idx += 128) {
        int m = idx >> 4, e = idx & 15;
        ms[m * 17 + e] = emb_mhc[mhc_x[n * MMH + m] * EE + e] + pe_val(m, e);
    }
    __syncthreads();
    for (int idx = t; idx < LP * MMH; idx += 128) {
        int l = idx / MMH, m = idx - l * MMH;
        float s = 0.f;
        #pragma unroll
        for (int e = 0; e < EE; ++e) s = fmaf(ps[l * 17 + e], ms[m * 17 + e], s);
        G[(size_t)n * GSTR + idx] = s;
    }
}

// ---------------- pack conv weights: fold BN scale, zero-pad K, slot-2 k-reversal ----------------
struct PackArgs {
    const float* w[2][3];
    const float* b[2][3];
    const float* g[2][3];
    const float* be[2][3];
    float* Wp;
    float* bp;
};

__global__ __launch_bounds__(256) void k_pack(PackArgs A) {
    int s = blockIdx.x, j = blockIdx.y, t = threadIdx.x;
    int K = KS_c[j], Kc = KC_c[j], nc = NC_c[j];
    int fam = (s == 0) ? 0 : 1;
    const float* w  = A.w[fam][j];
    const float* b  = A.b[fam][j];
    const float* g  = A.g[fam][j];
    const float* be = A.be[fam][j];
    const int pkoff[3] = {PK_J0, PK_J1, PK_J2};
    const int bpoff[3] = {BP_J0, BP_J1, BP_J2};
    float* Wp = A.Wp + s * PK_SLOT + pkoff[j];
    float* bp = A.bp + s * BP_SLOT + bpoff[j];
    float rs = rsqrtf(1.0f + 1e-5f);
    int tot = nc * Kc;
    for (int idx = t; idx < tot; idx += 256) {
        int c = idx / Kc, col = idx - c * Kc;
        float v = 0.f;
        if (col < K * MMH) {
            int k = col / MMH, m = col - k * MMH;
            int kk = (s == 2) ? (K - 1 - k) : k;
            v = w[((size_t)c * K + kk) * MMH + m] * (g[c] * rs);
        }
        Wp[idx] = v;
    }
    for (int c = t; c < nc; c += 256)
        bp[c] = b[c] * (g[c] * rs) + be[c];
}

// ---------------- pack MLP weights to bf16 with BN scale folded ----------------
__global__ __launch_bounds__(256) void k_packmlp(
    const float* __restrict__ w, const float* __restrict__ b,
    const float* __restrict__ g, const float* __restrict__ be,
    ushort* __restrict__ Wb, float* __restrict__ bp, int Co, int Ci)
{
    float rs = rsqrtf(1.0f + 1e-5f);
    int tot = Co * Ci;
    for (int idx = blockIdx.x * 256 + threadIdx.x; idx < tot; idx += gridDim.x * 256) {
        int o = idx / Ci;
        float v = w[idx] * (g[o] * rs);
        __hip_bfloat16 hb = __float2bfloat16(v);
        Wb[idx] = *reinterpret_cast<ushort*>(&hb);
    }
    if (blockIdx.x == 0)
        for (int o = threadIdx.x; o < Co; o += 256)
            bp[o] = b[o] * (g[o] * rs) + be[o];
}

// ---------------- conv as GEMM over windowed-G rows (bf16 output) ----------------
__global__ __launch_bounds__(256) void k_cgemm(
    const float* __restrict__ G, int n0, int off, int nkt, int Kc,
    const float* __restrict__ Wp, const float* __restrict__ bp,
    ushort* __restrict__ Xb, int C0)
{
    __shared__ __align__(16) float As[16][132];
    __shared__ __align__(16) float Bs[16][132];
    int t  = threadIdx.x;
    int p0 = blockIdx.x * 128;
    int o0 = blockIdx.y * 128;

    int lr0 = t >> 2, lq = t & 3;
    int lr1 = lr0 + 64;
    int ty = t >> 4, tx = t & 15;

    int pl0 = p0 + lr0, pl1 = p0 + lr1;
    int nA0 = n0 + pl0 / LO, iA0 = pl0 % LO;
    int nA1 = n0 + pl1 / LO, iA1 = pl1 % LO;
    size_t ab0 = (size_t)nA0 * GSTR + (off + iA0) * MMH;
    size_t ab1 = (size_t)nA1 * GSTR + (off + iA1) * MMH;

    float acc[8][8];
    #pragma unroll
    for (int u = 0; u < 8; ++u)
        #pragma unroll
        for (int v = 0; v < 8; ++v) acc[u][v] = 0.f;

    for (int kt = 0; kt < nkt; ++kt) {
        int k0 = kt << 4;
        float2 a0lo = *(const float2*)&G[ab0 + k0 + lq * 4];
        float2 a0hi = *(const float2*)&G[ab0 + k0 + lq * 4 + 2];
        float2 a1lo = *(const float2*)&G[ab1 + k0 + lq * 4];
        float2 a1hi = *(const float2*)&G[ab1 + k0 + lq * 4 + 2];
        float4 b0 = *(const float4*)&Wp[(size_t)(o0 + lr0) * Kc + k0 + lq * 4];
        float4 b1 = *(const float4*)&Wp[(size_t)(o0 + lr1) * Kc + k0 + lq * 4];
        __syncthreads();
        As[lq * 4 + 0][lr0] = a0lo.x; As[lq * 4 + 1][lr0] = a0lo.y;
        As[lq * 4 + 2][lr0] = a0hi.x; As[lq * 4 + 3][lr0] = a0hi.y;
        As[lq * 4 + 0][lr1] = a1lo.x; As[lq * 4 + 1][lr1] = a1lo.y;
        As[lq * 4 + 2][lr1] = a1hi.x; As[lq * 4 + 3][lr1] = a1hi.y;
        Bs[lq * 4 + 0][lr0] = b0.x; Bs[lq * 4 + 1][lr0] = b0.y;
        Bs[lq * 4 + 2][lr0] = b0.z; Bs[lq * 4 + 3][lr0] = b0.w;
        Bs[lq * 4 + 0][lr1] = b1.x; Bs[lq * 4 + 1][lr1] = b1.y;
        Bs[lq * 4 + 2][lr1] = b1.z; Bs[lq * 4 + 3][lr1] = b1.w;
        __syncthreads();
        #pragma unroll
        for (int kk = 0; kk < 16; ++kk) {
            float a_[8], b_[8];
            *(float4*)&a_[0] = *(const float4*)&As[kk][ty * 8];
            *(float4*)&a_[4] = *(const float4*)&As[kk][ty * 8 + 4];
            *(float4*)&b_[0] = *(const float4*)&Bs[kk][tx * 8];
            *(float4*)&b_[4] = *(const float4*)&Bs[kk][tx * 8 + 4];
            #pragma unroll
            for (int u = 0; u < 8; ++u)
                #pragma unroll
                for (int v = 0; v < 8; ++v)
                    acc[u][v] = fmaf(a_[u], b_[v], acc[u][v]);
        }
    }

    float bcol[8];
    #pragma unroll
    for (int v = 0; v < 8; ++v) bcol[v] = bp[o0 + tx * 8 + v];
    #pragma unroll
    for (int u = 0; u < 8; ++u) {
        int p = p0 + ty * 8 + u;
        ushort ob[8];
        #pragma unroll
        for (int v = 0; v < 8; ++v) {
            float val = fmaxf(acc[u][v] + bcol[v], 0.f);
            __hip_bfloat16 hb = __float2bfloat16(val);
            ob[v] = *reinterpret_cast<ushort*>(&hb);
        }
        *(s8v*)&Xb[(size_t)p * CT + C0 + o0 + tx * 8] = *(const s8v*)ob;
    }
}

// ---------------- bf16 MFMA GEMM, 128x128 tile, BK=32, bias+relu epilogue ----------------
// OUTB=1: write bf16 to Yb; OUTB=0: write f32 to Yf.
template<int OUTB>
__global__ __launch_bounds__(256) void k_mgemm(
    const ushort* __restrict__ Xb, int Cin,
    const ushort* __restrict__ Wb, const float* __restrict__ bp,
    ushort* __restrict__ Yb, float* __restrict__ Yf, int Cout)
{
    __shared__ ushort Al[128 * 40];    // +8 bf16 pad: row stride 80B -> 2-way max
    __shared__ ushort Bl[128 * 40];
    int t = threadIdx.x;
    int p0 = blockIdx.x * 128, o0 = blockIdx.y * 128;
    int lane = t & 63, w = t >> 6;
    int r0 = (w >> 1) * 64, c0 = (w & 1) * 64;

    f4v acc[4][4];
    #pragma unroll
    for (int m = 0; m < 4; ++m)
        #pragma unroll
        for (int n = 0; n < 4; ++n)
            acc[m][n] = (f4v){0.f, 0.f, 0.f, 0.f};

    int nkt = Cin >> 5;
    for (int kt = 0; kt < nkt; ++kt) {
        int k0 = kt << 5;
        __syncthreads();
        #pragma unroll
        for (int h = 0; h < 2; ++h) {
            int L = t + h * 256;
            int row = L >> 2, seg = L & 3;
            *(s8v*)&Al[row * 40 + seg * 8] =
                *(const s8v*)&Xb[(size_t)(p0 + row) * Cin + k0 + seg * 8];
            *(s8v*)&Bl[row * 40 + seg * 8] =
                *(const s8v*)&Wb[(size_t)(o0 + row) * Cin + k0 + seg * 8];
        }
        __syncthreads();
        s8v a[4], b[4];
        #pragma unroll
        for (int m = 0; m < 4; ++m)
            a[m] = *(const s8v*)&Al[(r0 + m * 16 + (lane & 15)) * 40 + (lane >> 4) * 8];
        #pragma unroll
        for (int n = 0; n < 4; ++n)
            b[n] = *(const s8v*)&Bl[(c0 + n * 16 + (lane & 15)) * 40 + (lane >> 4) * 8];
        #pragma unroll
        for (int m = 0; m < 4; ++m)
            #pragma unroll
            for (int n = 0; n < 4; ++n)
                acc[m][n] = __builtin_amdgcn_mfma_f32_16x16x32_bf16(a[m], b[n], acc[m][n], 0, 0, 0);
    }

    int cl = lane & 15, rq = lane >> 4;
    #pragma unroll
    for (int m = 0; m < 4; ++m) {
        #pragma unroll
        for (int n = 0; n < 4; ++n) {
            int o = o0 + c0 + n * 16 + cl;
            float bv = bp[o];
            #pragma unroll
            for (int j = 0; j < 4; ++j) {
                int p = p0 + r0 + m * 16 + rq * 4 + j;
                float v = fmaxf(acc[m][n][j] + bv, 0.f);
                if (OUTB) {
                    __hip_bfloat16 hb = __float2bfloat16(v);
                    Yb[(size_t)p * Cout + o] = *reinterpret_cast<ushort*>(&hb);
                } else {
                    Yf[(size_t)p * Cout + o] = v;
                }
            }
        }
    }
}

// ---------------- masked max-pool over i for one slot/chunk ----------------
__global__ __launch_bounds__(128) void k_pool(
    const float* __restrict__ Zc, const int* __restrict__ pep_x,
    float* __restrict__ pool, int n0, int slot)
{
    int nloc = blockIdx.x;
    int n = n0 + nloc;
    int c = blockIdx.y * 128 + threadIdx.x;
    float m = -INFINITY;
    for (int i = 0; i < LO; ++i)
        if (pep_x[n * LP + 3 + i] != 0)
            m = fmaxf(m, Zc[(size_t)(nloc * LO + i) * H2 + c]);
    pool[(size_t)n * (3 * H2) + slot * H2 + c] = m;
}

// ---------------- attention head per sample ----------------
__global__ __launch_bounds__(256) void k_poolhead(
    const float* __restrict__ pool,
    const float* __restrict__ w_att1, const float* __restrict__ b_att1,
    const float* __restrict__ w_att2, const float* __restrict__ b_att2,
    const float* __restrict__ w_out, const float* __restrict__ b_out,
    float* __restrict__ a_out, float* __restrict__ s2_out)
{
    int n = blockIdx.x, c = threadIdx.x;
    __shared__ float feat_s[H2];
    __shared__ float red[7][H2];
    __shared__ float sc_s[6];

    float mx[3];
    #pragma unroll
    for (int w = 0; w < 3; ++w)
        mx[w] = pool[(size_t)n * (3 * H2) + w * H2 + c];

    float fv = (mx[0] + mx[1] + mx[2]) * (1.f / 3.f);
    feat_s[c] = fv;
    #pragma unroll
    for (int o = 0; o < 2; ++o)
        #pragma unroll
        for (int w = 0; w < 3; ++w)
            red[o * 3 + w][c] = w_out[o * H2 + c] * mx[w];
    __syncthreads();

    float hacc = 0.f;
    for (int cc = 0; cc < H2; ++cc)
        hacc = fmaf(w_att1[(size_t)c * H2 + cc], feat_s[cc], hacc);
    float h = tanhf(hacc + b_att1[c]);
    red[6][c] = h * w_att2[c];
    __syncthreads();

    for (int s = 128; s > 0; s >>= 1) {
        if (c < s) {
            #pragma unroll
            for (int jj = 0; jj < 7; ++jj) red[jj][c] += red[jj][c + s];
        }
        __syncthreads();
    }
    if (c == 0) a_out[n] = red[6][0] + b_att2[0];
    if (c < 6) {
        float x = red[c][0] + b_out[c / 3];
        sc_s[c] = 1.f / (1.f + expf(-x));
    }
    __syncthreads();
    if (c < 2) {
        float half = 0.5f * (sc_s[c * 3 + 0] + sc_s[c * 3 + 1]);
        s2_out[n * 2 + c] = fmaxf(half, sc_s[c * 3 + 2]);   // inverse==1 path
    }
}

// ---------------- bag segment softmax + weighted sum ----------------
__global__ __launch_bounds__(1024) void k_final(
    const float* __restrict__ a_in, const float* __restrict__ s2_in,
    const int* __restrict__ bags, float* __restrict__ out)
{
    __shared__ float a_s[NS], s0_s[NS], s1_s[NS];
    __shared__ int off_s[33];
    int t = threadIdx.x;
    a_s[t]  = a_in[t];
    s0_s[t] = s2_in[t * 2 + 0];
    s1_s[t] = s2_in[t * 2 + 1];
    if (t == 0) {
        off_s[0] = 0;
        for (int g = 0; g < 32; ++g) off_s[g + 1] = off_s[g] + bags[g];
    }
    __syncthreads();
    if (t < 32) {
        int st = off_s[t], en = off_s[t + 1];
        float mxv = -INFINITY;
        for (int n = st; n < en; ++n) mxv = fmaxf(mxv, a_s[n]);
        float se = 0.f;
        for (int n = st; n < en; ++n) se += expf(a_s[n] - mxv);
        float inv = 1.f / se;
        float o0 = 0.f, o1 = 0.f;
        for (int n = st; n < en; ++n) {
            float w = expf(a_s[n] - mxv) * inv;
            o0 += w * s0_s[n];
            o1 += w * s1_s[n];
        }
        out[t * 2 + 0] = fminf(fmaxf(o0, 0.f), 1.f);
        out[t * 2 + 1] = fminf(fmaxf(o1, 0.f), 1.f);
    }
}

extern "C" void kernel_launch(void* const* d_in, const int* in_sizes, int n_in,
                              void* d_out, int out_size, void* d_ws, size_t ws_size,
                              hipStream_t stream) {
    const int* pep_x = (const int*)d_in[0];
    const int* mhc_x = (const int*)d_in[1];
    const int* bags  = (const int*)d_in[4];
    const float* emb_pep = (const float*)d_in[6];
    const float* emb_mhc = (const float*)d_in[7];

    char* wsb = (char*)d_ws;
    // byte-offset workspace layout
    float*  pool   = (float*) (wsb + 0);          // 3,145,728 B
    float*  a_buf  = (float*) (wsb + 3145728);    //     4,096 B
    float*  s2_buf = (float*) (wsb + 3149824);    //     8,192 B
    float*  Wpack  = (float*) (wsb + 3158016);    // 1,449,984 B
    float*  bpack  = (float*) (wsb + 4608000);    //     7,680 B
    ushort* Wmlp   = (ushort*)(wsb + 4615680);    // 1,835,008 B
    float*  bmlp   = (float*) (wsb + 6450688);    //     6,144 B
    float*  G      = (float*) (wsb + 6456832);    // 3,760,384 B (incl slack)
    const size_t XB_B = 10217216;

    // choose chunk size (samples per chunk) to fit ws_size
    int Cn = 1024;
    while (Cn > 128) {
        size_t need = XB_B + (size_t)Cn * LO * (1280 + 1024 + 1024);
        if (need <= ws_size) break;
        Cn >>= 1;
    }
    int R = Cn * LO;
    ushort* Xb = (ushort*)(wsb + XB_B);                       // R*640 bf16
    ushort* Yb = (ushort*)((char*)Xb + (size_t)R * 1280);     // R*512 bf16
    float*  Zc = (float*) ((char*)Yb + (size_t)R * 1024);     // R*256 f32

    k_embG<<<dim3(NS), dim3(128), 0, stream>>>(pep_x, mhc_x, emb_pep, emb_mhc, G);

    PackArgs pa;
    for (int j = 0; j < 3; ++j) {
        pa.w[0][j]  = (const float*)d_in[8 + 4 * j];
        pa.b[0][j]  = (const float*)d_in[9 + 4 * j];
        pa.g[0][j]  = (const float*)d_in[10 + 4 * j];
        pa.be[0][j] = (const float*)d_in[11 + 4 * j];
        pa.w[1][j]  = (const float*)d_in[20 + 4 * j];
        pa.b[1][j]  = (const float*)d_in[21 + 4 * j];
        pa.g[1][j]  = (const float*)d_in[22 + 4 * j];
        pa.be[1][j] = (const float*)d_in[23 + 4 * j];
    }
    pa.Wp = Wpack; pa.bp = bpack;
    k_pack<<<dim3(3, 3), dim3(256), 0, stream>>>(pa);

    // pack MLP weights (fold BN scale) to bf16: fam 0 = lins_f (d_in 32..39), fam 1 = lins_r (40..47)
    for (int fam = 0; fam < 2; ++fam) {
        int base = fam ? 40 : 32;
        k_packmlp<<<dim3(64), dim3(256), 0, stream>>>(
            (const float*)d_in[base + 0], (const float*)d_in[base + 1],
            (const float*)d_in[base + 2], (const float*)d_in[base + 3],
            Wmlp + fam * 458752, bmlp + fam * 768, H1, CT);
        k_packmlp<<<dim3(32), dim3(256), 0, stream>>>(
            (const float*)d_in[base + 4], (const float*)d_in[base + 5],
            (const float*)d_in[base + 6], (const float*)d_in[base + 7],
            Wmlp + fam * 458752 + 327680, bmlp + fam * 768 + 512, H2, H1);
    }

    const int pkoff[3] = {PK_J0, PK_J1, PK_J2};
    const int bpoff[3] = {BP_J0, BP_J1, BP_J2};
    const int KC_[3]   = {112, 176, 240};
    const int OFF_[3]  = {2, 1, 0};
    const int NC_[3]   = {128, 256, 256};
    const int C0_[3]   = {0, 128, 384};

    for (int slot = 0; slot < 3; ++slot) {
        int fam = (slot == 0) ? 0 : 1;
        const ushort* wA  = Wmlp + fam * 458752;
        const float*  bpA = bmlp + fam * 768;
        const ushort* wB  = Wmlp + fam * 458752 + 327680;
        const float*  bpB = bmlp + fam * 768 + 512;

        for (int n0 = 0; n0 < NS; n0 += Cn) {
            for (int j = 0; j < 3; ++j) {
                k_cgemm<<<dim3(R / 128, NC_[j] / 128), dim3(256), 0, stream>>>(
                    G, n0, OFF_[j], KC_[j] / 16, KC_[j],
                    Wpack + slot * PK_SLOT + pkoff[j],
                    bpack + slot * BP_SLOT + bpoff[j],
                    Xb, C0_[j]);
            }
            k_mgemm<1><<<dim3(R / 128, H1 / 128), dim3(256), 0, stream>>>(
                Xb, CT, wA, bpA, Yb, nullptr, H1);
            k_mgemm<0><<<dim3(R / 128, H2 / 128), dim3(256), 0, stream>>>(
                Yb, H1, wB, bpB, nullptr, Zc, H2);
            k_pool<<<dim3(Cn, H2 / 128), dim3(128), 0, stream>>>(
                Zc, pep_x, pool, n0, slot);
        }
    }

    k_poolhead<<<dim3(NS), dim3(256), 0, stream>>>(
        pool,
        (const float*)d_in[48], (const float*)d_in[49], (const float*)d_in[50], (const float*)d_in[51],
        (const float*)d_in[52], (const float*)d_in[53],
        a_buf, s2_buf);

    k_final<<<dim3(1), dim3(1024), 0, stream>>>(a_buf, s2_buf, bags, (float*)d_out);
}

// Round 8
// 312.454 us; speedup vs baseline: 8.4873x; 1.9914x over previous
//
#include <hip/hip_runtime.h>
#include <hip/hip_bf16.h>
#include <math.h>

#define NS   1024
#define LP   27
#define MMH  34
#define EE   16
#define LO   21
#define CT   640
#define H1   512
#define H2   256
#define LPAD 40
#define GROW (LP*LPAD)      // 1080 bf16 els per sample

typedef __attribute__((ext_vector_type(8))) short  s8v;
typedef __attribute__((ext_vector_type(4))) float  f4v;

// packed conv-weight geometry: col = k*40 + m, Kcp = K*40 padded to mult-32
// j:    0    1    2
// K:    3    5    7
// Kcp:  128  224  288
// nc:   128  256  256
#define PK2_SLOT 147456     // 128*128 + 256*224 + 256*288
#define PK2_J0   0
#define PK2_J1   16384
#define PK2_J2   73728

__device__ __forceinline__ ushort f2b(float v) {
    __hip_bfloat16 hb = __float2bfloat16(v);
    return *reinterpret_cast<ushort*>(&hb);
}

// sinusoidal positional encoding value, matching numpy _pe()
__device__ __forceinline__ float pe_val(int pos, int e) {
    int j = e >> 1;
    float div = expf(-1.1512925464970229f * (float)j);  // 10000^(-j/8)
    float ang = (float)pos * div;
    return (e & 1) ? cosf(ang) : sinf(ang);
}

// ---------------- Gb[n,l,m] = bf16( sum_e pep_e[n,l,e]*mhc_e[n,m,e] ), m-padded to 40 ----------------
__global__ __launch_bounds__(128) void k_embG(
    const int* __restrict__ pep_x, const int* __restrict__ mhc_x,
    const float* __restrict__ emb_pep, const float* __restrict__ emb_mhc,
    ushort* __restrict__ Gb)
{
    int n = blockIdx.x, t = threadIdx.x;
    __shared__ float ps[LP * 17];
    __shared__ float ms[MMH * 17];
    for (int idx = t; idx < LP * EE; idx += 128) {
        int l = idx >> 4, e = idx & 15;
        float v = emb_pep[pep_x[n * LP + l] * EE + e];
        if (l >= 3 && l < 24) v += pe_val(l - 3, e);
        ps[l * 17 + e] = v;
    }
    for (int idx = t; idx < MMH * EE; idx += 128) {
        int m = idx >> 4, e = idx & 15;
        ms[m * 17 + e] = emb_mhc[mhc_x[n * MMH + m] * EE + e] + pe_val(m, e);
    }
    __syncthreads();
    for (int idx = t; idx < GROW; idx += 128) {
        int l = idx / LPAD, m = idx - l * LPAD;
        float s = 0.f;
        if (m < MMH) {
            #pragma unroll
            for (int e = 0; e < EE; ++e) s = fmaf(ps[l * 17 + e], ms[m * 17 + e], s);
        }
        Gb[(size_t)n * GROW + idx] = f2b(s);
    }
    if (n == 0 && t < 64) Gb[(size_t)NS * GROW + t] = 0;   // slack row for j=2 overread
}

// ---------------- pack conv weights -> bf16 [nc][Kcp]; fold BN scale; slot-2 k-reversal ----------------
struct PackArgs {
    const float* w[2][3];
    const float* b[2][3];
    const float* g[2][3];
    const float* be[2][3];
    ushort* Wp;
    float* bp;
};

__global__ __launch_bounds__(256) void k_pack(PackArgs A) {
    const int KS_[3]  = {3, 5, 7};
    const int KCP_[3] = {128, 224, 288};
    const int NC_[3]  = {128, 256, 256};
    const int pkoff[3] = {PK2_J0, PK2_J1, PK2_J2};
    const int bpoff[3] = {0, 128, 384};
    int s = blockIdx.x, j = blockIdx.y, t = threadIdx.x;
    int K = KS_[j], Kcp = KCP_[j], nc = NC_[j];
    int fam = (s == 0) ? 0 : 1;
    const float* w  = A.w[fam][j];
    const float* b  = A.b[fam][j];
    const float* g  = A.g[fam][j];
    const float* be = A.be[fam][j];
    ushort* Wp = A.Wp + s * PK2_SLOT + pkoff[j];
    float*  bp = A.bp + s * CT + bpoff[j];
    float rs = rsqrtf(1.0f + 1e-5f);
    int tot = nc * Kcp;
    for (int idx = blockIdx.z * 256 + t; idx < tot; idx += gridDim.z * 256) {
        int c = idx / Kcp, col = idx - c * Kcp;
        int k = col / LPAD, m = col - k * LPAD;
        float v = 0.f;
        if (k < K && m < MMH) {
            int kk = (s == 2) ? (K - 1 - k) : k;
            v = w[((size_t)c * K + kk) * MMH + m] * (g[c] * rs);
        }
        Wp[idx] = f2b(v);
    }
    if (blockIdx.z == 0)
        for (int c = t; c < nc; c += 256)
            bp[c] = b[c] * (g[c] * rs) + be[c];
}

// ---------------- pack MLP weights to bf16 with BN scale folded ----------------
__global__ __launch_bounds__(256) void k_packmlp(
    const float* __restrict__ w, const float* __restrict__ b,
    const float* __restrict__ g, const float* __restrict__ be,
    ushort* __restrict__ Wb, float* __restrict__ bp, int Co, int Ci)
{
    float rs = rsqrtf(1.0f + 1e-5f);
    int tot = Co * Ci;
    for (int idx = blockIdx.x * 256 + threadIdx.x; idx < tot; idx += gridDim.x * 256) {
        int o = idx / Ci;
        Wb[idx] = f2b(w[idx] * (g[o] * rs));
    }
    if (blockIdx.x == 0)
        for (int o = threadIdx.x; o < Co; o += 256)
            bp[o] = b[o] * (g[o] * rs) + be[o];
}

// ---------------- conv as bf16 MFMA GEMM over windowed-Gb rows, all 3 j merged ----------------
struct CArgs { const ushort* Gb; const ushort* Wp; const float* bp; ushort* Xb; int n0; };

__global__ __launch_bounds__(256) void k_cmfma(CArgs A) {
    const int kcpm[5] = {128, 224, 224, 288, 288};
    const int offm[5] = {2, 1, 1, 0, 0};
    const int o0m[5]  = {0, 0, 128, 0, 128};
    const int c0m[5]  = {0, 128, 128, 384, 384};   // X column base of j
    const int wofm[5] = {PK2_J0, PK2_J1, PK2_J1, PK2_J2, PK2_J2};

    __shared__ ushort Al[128 * 40];
    __shared__ ushort Bl[128 * 40];
    int y = blockIdx.y;
    int Kcp = kcpm[y], off = offm[y], o0 = o0m[y];
    const ushort* Wt = A.Wp + wofm[y] + (size_t)o0 * Kcp;
    int t = threadIdx.x, lane = t & 63, w = t >> 6;
    int r0 = (w >> 1) * 64, c0w = (w & 1) * 64;
    int p0 = blockIdx.x * 128;

    int row_a = t >> 2, seg = t & 3;
    int p_r0 = p0 + row_a, p_r1 = p_r0 + 64;
    size_t wb0 = (size_t)(A.n0 + p_r0 / LO) * GROW + (off + p_r0 % LO) * LPAD;
    size_t wb1 = (size_t)(A.n0 + p_r1 / LO) * GROW + (off + p_r1 % LO) * LPAD;

    f4v acc[4][4];
    #pragma unroll
    for (int m = 0; m < 4; ++m)
        #pragma unroll
        for (int n = 0; n < 4; ++n)
            acc[m][n] = (f4v){0.f, 0.f, 0.f, 0.f};

    int nkt = Kcp >> 5;
    for (int kt = 0; kt < nkt; ++kt) {
        int k0 = kt << 5;
        __syncthreads();
        *(s8v*)&Al[row_a * 40 + seg * 8]        = *(const s8v*)&A.Gb[wb0 + k0 + seg * 8];
        *(s8v*)&Al[(row_a + 64) * 40 + seg * 8] = *(const s8v*)&A.Gb[wb1 + k0 + seg * 8];
        *(s8v*)&Bl[row_a * 40 + seg * 8]        = *(const s8v*)&Wt[(size_t)row_a * Kcp + k0 + seg * 8];
        *(s8v*)&Bl[(row_a + 64) * 40 + seg * 8] = *(const s8v*)&Wt[(size_t)(row_a + 64) * Kcp + k0 + seg * 8];
        __syncthreads();
        s8v a[4], b[4];
        #pragma unroll
        for (int m = 0; m < 4; ++m)
            a[m] = *(const s8v*)&Al[(r0 + m * 16 + (lane & 15)) * 40 + (lane >> 4) * 8];
        #pragma unroll
        for (int n = 0; n < 4; ++n)
            b[n] = *(const s8v*)&Bl[(c0w + n * 16 + (lane & 15)) * 40 + (lane >> 4) * 8];
        #pragma unroll
        for (int m = 0; m < 4; ++m)
            #pragma unroll
            for (int n = 0; n < 4; ++n)
                acc[m][n] = __builtin_amdgcn_mfma_f32_16x16x32_bf16(a[m], b[n], acc[m][n], 0, 0, 0);
    }

    int cl = lane & 15, rq = lane >> 4;
    #pragma unroll
    for (int m = 0; m < 4; ++m) {
        #pragma unroll
        for (int n = 0; n < 4; ++n) {
            int oc = c0m[y] + o0 + c0w + n * 16 + cl;    // column in X / bias index
            float bv = A.bp[oc];
            #pragma unroll
            for (int j = 0; j < 4; ++j) {
                int p = p0 + r0 + m * 16 + rq * 4 + j;
                A.Xb[(size_t)p * CT + oc] = f2b(fmaxf(acc[m][n][j] + bv, 0.f));
            }
        }
    }
}

// ---------------- bf16 MFMA GEMM, 128x128 tile, BK=32, bias+relu epilogue ----------------
template<int OUTB>
__global__ __launch_bounds__(256) void k_mgemm(
    const ushort* __restrict__ Xb, int Cin,
    const ushort* __restrict__ Wb, const float* __restrict__ bp,
    ushort* __restrict__ Yb, float* __restrict__ Yf, int Cout)
{
    __shared__ ushort Al[128 * 40];
    __shared__ ushort Bl[128 * 40];
    int t = threadIdx.x;
    int p0 = blockIdx.x * 128, o0 = blockIdx.y * 128;
    int lane = t & 63, w = t >> 6;
    int r0 = (w >> 1) * 64, c0 = (w & 1) * 64;

    f4v acc[4][4];
    #pragma unroll
    for (int m = 0; m < 4; ++m)
        #pragma unroll
        for (int n = 0; n < 4; ++n)
            acc[m][n] = (f4v){0.f, 0.f, 0.f, 0.f};

    int nkt = Cin >> 5;
    for (int kt = 0; kt < nkt; ++kt) {
        int k0 = kt << 5;
        __syncthreads();
        #pragma unroll
        for (int h = 0; h < 2; ++h) {
            int L = t + h * 256;
            int row = L >> 2, seg = L & 3;
            *(s8v*)&Al[row * 40 + seg * 8] =
                *(const s8v*)&Xb[(size_t)(p0 + row) * Cin + k0 + seg * 8];
            *(s8v*)&Bl[row * 40 + seg * 8] =
                *(const s8v*)&Wb[(size_t)(o0 + row) * Cin + k0 + seg * 8];
        }
        __syncthreads();
        s8v a[4], b[4];
        #pragma unroll
        for (int m = 0; m < 4; ++m)
            a[m] = *(const s8v*)&Al[(r0 + m * 16 + (lane & 15)) * 40 + (lane >> 4) * 8];
        #pragma unroll
        for (int n = 0; n < 4; ++n)
            b[n] = *(const s8v*)&Bl[(c0 + n * 16 + (lane & 15)) * 40 + (lane >> 4) * 8];
        #pragma unroll
        for (int m = 0; m < 4; ++m)
            #pragma unroll
            for (int n = 0; n < 4; ++n)
                acc[m][n] = __builtin_amdgcn_mfma_f32_16x16x32_bf16(a[m], b[n], acc[m][n], 0, 0, 0);
    }

    int cl = lane & 15, rq = lane >> 4;
    #pragma unroll
    for (int m = 0; m < 4; ++m) {
        #pragma unroll
        for (int n = 0; n < 4; ++n) {
            int o = o0 + c0 + n * 16 + cl;
            float bv = bp[o];
            #pragma unroll
            for (int j = 0; j < 4; ++j) {
                int p = p0 + r0 + m * 16 + rq * 4 + j;
                float v = fmaxf(acc[m][n][j] + bv, 0.f);
                if (OUTB) {
                    Yb[(size_t)p * Cout + o] = f2b(v);
                } else {
                    Yf[(size_t)p * Cout + o] = v;
                }
            }
        }
    }
}

// ---------------- masked max-pool over i for one slot/chunk ----------------
__global__ __launch_bounds__(128) void k_pool(
    const float* __restrict__ Zc, const int* __restrict__ pep_x,
    float* __restrict__ pool, int n0, int slot)
{
    int nloc = blockIdx.x;
    int n = n0 + nloc;
    int c = blockIdx.y * 128 + threadIdx.x;
    float m = -INFINITY;
    for (int i = 0; i < LO; ++i)
        if (pep_x[n * LP + 3 + i] != 0)
            m = fmaxf(m, Zc[(size_t)(nloc * LO + i) * H2 + c]);
    pool[(size_t)n * (3 * H2) + slot * H2 + c] = m;
}

// ---------------- attention head per sample ----------------
__global__ __launch_bounds__(256) void k_poolhead(
    const float* __restrict__ pool,
    const float* __restrict__ w_att1, const float* __restrict__ b_att1,
    const float* __restrict__ w_att2, const float* __restrict__ b_att2,
    const float* __restrict__ w_out, const float* __restrict__ b_out,
    float* __restrict__ a_out, float* __restrict__ s2_out)
{
    int n = blockIdx.x, c = threadIdx.x;
    __shared__ float feat_s[H2];
    __shared__ float red[7][H2];
    __shared__ float sc_s[6];

    float mx[3];
    #pragma unroll
    for (int w = 0; w < 3; ++w)
        mx[w] = pool[(size_t)n * (3 * H2) + w * H2 + c];

    float fv = (mx[0] + mx[1] + mx[2]) * (1.f / 3.f);
    feat_s[c] = fv;
    #pragma unroll
    for (int o = 0; o < 2; ++o)
        #pragma unroll
        for (int w = 0; w < 3; ++w)
            red[o * 3 + w][c] = w_out[o * H2 + c] * mx[w];
    __syncthreads();

    float hacc = 0.f;
    for (int cc = 0; cc < H2; ++cc)
        hacc = fmaf(w_att1[(size_t)c * H2 + cc], feat_s[cc], hacc);
    float h = tanhf(hacc + b_att1[c]);
    red[6][c] = h * w_att2[c];
    __syncthreads();

    for (int s = 128; s > 0; s >>= 1) {
        if (c < s) {
            #pragma unroll
            for (int jj = 0; jj < 7; ++jj) red[jj][c] += red[jj][c + s];
        }
        __syncthreads();
    }
    if (c == 0) a_out[n] = red[6][0] + b_att2[0];
    if (c < 6) {
        float x = red[c][0] + b_out[c / 3];
        sc_s[c] = 1.f / (1.f + expf(-x));
    }
    __syncthreads();
    if (c < 2) {
        float half = 0.5f * (sc_s[c * 3 + 0] + sc_s[c * 3 + 1]);
        s2_out[n * 2 + c] = fmaxf(half, sc_s[c * 3 + 2]);   // inverse==1 path
    }
}

// ---------------- bag segment softmax + weighted sum ----------------
__global__ __launch_bounds__(1024) void k_final(
    const float* __restrict__ a_in, const float* __restrict__ s2_in,
    const int* __restrict__ bags, float* __restrict__ out)
{
    __shared__ float a_s[NS], s0_s[NS], s1_s[NS];
    __shared__ int off_s[33];
    int t = threadIdx.x;
    a_s[t]  = a_in[t];
    s0_s[t] = s2_in[t * 2 + 0];
    s1_s[t] = s2_in[t * 2 + 1];
    if (t == 0) {
        off_s[0] = 0;
        for (int g = 0; g < 32; ++g) off_s[g + 1] = off_s[g] + bags[g];
    }
    __syncthreads();
    if (t < 32) {
        int st = off_s[t], en = off_s[t + 1];
        float mxv = -INFINITY;
        for (int n = st; n < en; ++n) mxv = fmaxf(mxv, a_s[n]);
        float se = 0.f;
        for (int n = st; n < en; ++n) se += expf(a_s[n] - mxv);
        float inv = 1.f / se;
        float o0 = 0.f, o1 = 0.f;
        for (int n = st; n < en; ++n) {
            float w = expf(a_s[n] - mxv) * inv;
            o0 += w * s0_s[n];
            o1 += w * s1_s[n];
        }
        out[t * 2 + 0] = fminf(fmaxf(o0, 0.f), 1.f);
        out[t * 2 + 1] = fminf(fmaxf(o1, 0.f), 1.f);
    }
}

extern "C" void kernel_launch(void* const* d_in, const int* in_sizes, int n_in,
                              void* d_out, int out_size, void* d_ws, size_t ws_size,
                              hipStream_t stream) {
    const int* pep_x = (const int*)d_in[0];
    const int* mhc_x = (const int*)d_in[1];
    const int* bags  = (const int*)d_in[4];
    const float* emb_pep = (const float*)d_in[6];
    const float* emb_mhc = (const float*)d_in[7];

    char* wsb = (char*)d_ws;
    // byte-offset workspace layout (all 16B-aligned)
    float*  pool   = (float*) (wsb + 0);          // 3,145,728
    float*  a_buf  = (float*) (wsb + 3145728);    //     4,096
    float*  s2_buf = (float*) (wsb + 3149824);    //     8,192
    ushort* Wpack  = (ushort*)(wsb + 3158016);    //   884,736 (3*147456*2)
    float*  bpack  = (float*) (wsb + 4042752);    //     7,680
    ushort* Wmlp   = (ushort*)(wsb + 4050432);    // 1,835,008
    float*  bmlp   = (float*) (wsb + 5885440);    //     6,144
    ushort* Gb     = (ushort*)(wsb + 5891584);    // 2,211,968 ((1024*1080+64)*2)
    const size_t XB_B = 8103552;

    // choose chunk size (samples per chunk) to fit ws_size
    int Cn = 1024;
    while (Cn > 128) {
        size_t need = XB_B + (size_t)Cn * LO * (1280 + 1024 + 1024);
        if (need <= ws_size) break;
        Cn >>= 1;
    }
    int R = Cn * LO;
    ushort* Xb = (ushort*)(wsb + XB_B);                       // R*640 bf16
    ushort* Yb = (ushort*)((char*)Xb + (size_t)R * 1280);     // R*512 bf16
    float*  Zc = (float*) ((char*)Yb + (size_t)R * 1024);     // R*256 f32

    k_embG<<<dim3(NS), dim3(128), 0, stream>>>(pep_x, mhc_x, emb_pep, emb_mhc, Gb);

    PackArgs pa;
    for (int j = 0; j < 3; ++j) {
        pa.w[0][j]  = (const float*)d_in[8 + 4 * j];
        pa.b[0][j]  = (const float*)d_in[9 + 4 * j];
        pa.g[0][j]  = (const float*)d_in[10 + 4 * j];
        pa.be[0][j] = (const float*)d_in[11 + 4 * j];
        pa.w[1][j]  = (const float*)d_in[20 + 4 * j];
        pa.b[1][j]  = (const float*)d_in[21 + 4 * j];
        pa.g[1][j]  = (const float*)d_in[22 + 4 * j];
        pa.be[1][j] = (const float*)d_in[23 + 4 * j];
    }
    pa.Wp = Wpack; pa.bp = bpack;
    k_pack<<<dim3(3, 3, 16), dim3(256), 0, stream>>>(pa);

    // pack MLP weights (fold BN scale) to bf16: fam 0 = lins_f (32..39), fam 1 = lins_r (40..47)
    for (int fam = 0; fam < 2; ++fam) {
        int base = fam ? 40 : 32;
        k_packmlp<<<dim3(64), dim3(256), 0, stream>>>(
            (const float*)d_in[base + 0], (const float*)d_in[base + 1],
            (const float*)d_in[base + 2], (const float*)d_in[base + 3],
            Wmlp + fam * 458752, bmlp + fam * 768, H1, CT);
        k_packmlp<<<dim3(32), dim3(256), 0, stream>>>(
            (const float*)d_in[base + 4], (const float*)d_in[base + 5],
            (const float*)d_in[base + 6], (const float*)d_in[base + 7],
            Wmlp + fam * 458752 + 327680, bmlp + fam * 768 + 512, H2, H1);
    }

    for (int slot = 0; slot < 3; ++slot) {
        int fam = (slot == 0) ? 0 : 1;
        const ushort* wA  = Wmlp + fam * 458752;
        const float*  bpA = bmlp + fam * 768;
        const ushort* wB  = Wmlp + fam * 458752 + 327680;
        const float*  bpB = bmlp + fam * 768 + 512;

        for (int n0 = 0; n0 < NS; n0 += Cn) {
            CArgs ca;
            ca.Gb = Gb;
            ca.Wp = Wpack + slot * PK2_SLOT;
            ca.bp = bpack + slot * CT;
            ca.Xb = Xb;
            ca.n0 = n0;
            k_cmfma<<<dim3(R / 128, 5), dim3(256), 0, stream>>>(ca);
            k_mgemm<1><<<dim3(R / 128, H1 / 128), dim3(256), 0, stream>>>(
                Xb, CT, wA, bpA, Yb, nullptr, H1);
            k_mgemm<0><<<dim3(R / 128, H2 / 128), dim3(256), 0, stream>>>(
                Yb, H1, wB, bpB, nullptr, Zc, H2);
            k_pool<<<dim3(Cn, H2 / 128), dim3(128), 0, stream>>>(
                Zc, pep_x, pool, n0, slot);
        }
    }

    k_poolhead<<<dim3(NS), dim3(256), 0, stream>>>(
        pool,
        (const float*)d_in[48], (const float*)d_in[49], (const float*)d_in[50], (const float*)d_in[51],
        (const float*)d_in[52], (const float*)d_in[53],
        a_buf, s2_buf);

    k_final<<<dim3(1), dim3(1024), 0, stream>>>(a_buf, s2_buf, bags, (float*)d_out);
}

// Round 9
// 231.186 us; speedup vs baseline: 11.4709x; 1.3515x over previous
//
#include <hip/hip_runtime.h>
#include <hip/hip_bf16.h>
#include <math.h>

#define NS   1024
#define LP   27
#define MMH  34
#define EE   16
#define LO   21
#define CT   640
#define H1   512
#define H2   256
#define LPAD 40
#define GROW (LP*LPAD)      // 1080 bf16 els per sample
#define SLOTROWS (NS*LO)    // 21504
#define ALLROWS  (3*SLOTROWS)

typedef __attribute__((ext_vector_type(8))) short  s8v;
typedef __attribute__((ext_vector_type(4))) float  f4v;

// packed conv-weight geometry: col = k*40 + m, Kcp = K*40 padded to mult-32
#define PK2_SLOT 147456     // 128*128 + 256*224 + 256*288
#define PK2_J0   0
#define PK2_J1   16384
#define PK2_J2   73728
// MLP pack offsets
#define WMLP_FAM 458752     // 512*640 + 256*512
#define WMLP_B   327680     // 512*640
#define BMLP_FAM 768
#define BMLP_B   512

__device__ __forceinline__ ushort f2b(float v) {
    __hip_bfloat16 hb = __float2bfloat16(v);
    return *reinterpret_cast<ushort*>(&hb);
}

// sinusoidal positional encoding value, matching numpy _pe()
__device__ __forceinline__ float pe_val(int pos, int e) {
    int j = e >> 1;
    float div = expf(-1.1512925464970229f * (float)j);  // 10000^(-j/8)
    float ang = (float)pos * div;
    return (e & 1) ? cosf(ang) : sinf(ang);
}

// ---------------- fused prep: embG (blocks 0..1023) | conv pack (1024..1167) | mlp pack (1168..1279) ----------------
struct PrepArgs {
    const int* pep_x; const int* mhc_x;
    const float* emb_pep; const float* emb_mhc;
    const float* cw[2][3]; const float* cb[2][3]; const float* cg[2][3]; const float* cbe[2][3];
    const float* mw[4]; const float* mb[4]; const float* mg[4]; const float* mbe[4];
    ushort* Gb; ushort* Wpack; float* bpack; ushort* Wmlp; float* bmlp;
};

__global__ __launch_bounds__(256) void k_prep(PrepArgs A) {
    int b = blockIdx.x, t = threadIdx.x;
    float rs = rsqrtf(1.0f + 1e-5f);
    if (b < NS) {
        // ---- embG: Gb[n,l,m] = bf16(sum_e pep_e*mhc_e), m-padded to 40 ----
        __shared__ float ps[LP * 17];
        __shared__ float ms[MMH * 17];
        int n = b;
        for (int idx = t; idx < LP * EE; idx += 256) {
            int l = idx >> 4, e = idx & 15;
            float v = A.emb_pep[A.pep_x[n * LP + l] * EE + e];
            if (l >= 3 && l < 24) v += pe_val(l - 3, e);
            ps[l * 17 + e] = v;
        }
        for (int idx = t; idx < MMH * EE; idx += 256) {
            int m = idx >> 4, e = idx & 15;
            ms[m * 17 + e] = A.emb_mhc[A.mhc_x[n * MMH + m] * EE + e] + pe_val(m, e);
        }
        __syncthreads();
        for (int idx = t; idx < GROW; idx += 256) {
            int l = idx / LPAD, m = idx - l * LPAD;
            float s = 0.f;
            if (m < MMH) {
                #pragma unroll
                for (int e = 0; e < EE; ++e) s = fmaf(ps[l * 17 + e], ms[m * 17 + e], s);
            }
            A.Gb[(size_t)n * GROW + idx] = f2b(s);
        }
        if (n == 0 && t < 64) A.Gb[(size_t)NS * GROW + t] = 0;   // slack for j=2 overread
    } else if (b < NS + 144) {
        // ---- conv weight pack ----
        const int KS_[3]  = {3, 5, 7};
        const int KCP_[3] = {128, 224, 288};
        const int NC_[3]  = {128, 256, 256};
        const int pkoff[3] = {PK2_J0, PK2_J1, PK2_J2};
        const int bpoff[3] = {0, 128, 384};
        int lin = b - NS;
        int s = lin / 48, rem = lin - s * 48, j = rem >> 4, z = rem & 15;
        int K = KS_[j], Kcp = KCP_[j], nc = NC_[j];
        int fam = (s == 0) ? 0 : 1;
        const float* w  = A.cw[fam][j];
        const float* g  = A.cg[fam][j];
        ushort* Wp = A.Wpack + s * PK2_SLOT + pkoff[j];
        int tot = nc * Kcp;
        for (int idx = z * 256 + t; idx < tot; idx += 16 * 256) {
            int c = idx / Kcp, col = idx - c * Kcp;
            int k = col / LPAD, m = col - k * LPAD;
            float v = 0.f;
            if (k < K && m < MMH) {
                int kk = (s == 2) ? (K - 1 - k) : k;
                v = w[((size_t)c * K + kk) * MMH + m] * (g[c] * rs);
            }
            Wp[idx] = f2b(v);
        }
        if (z == 0) {
            const float* bb = A.cb[fam][j];
            const float* be = A.cbe[fam][j];
            float* bp = A.bpack + s * CT + bpoff[j];
            for (int c = t; c < nc; c += 256)
                bp[c] = bb[c] * (g[c] * rs) + be[c];
        }
    } else {
        // ---- mlp weight pack: tasks {fam0A, fam0B, fam1A, fam1B} ----
        int lin = b - NS - 144;   // 0..111
        int task, rel, nb;
        if (lin < 40)      { task = 0; rel = lin;      nb = 40; }
        else if (lin < 56) { task = 1; rel = lin - 40; nb = 16; }
        else if (lin < 96) { task = 2; rel = lin - 56; nb = 40; }
        else               { task = 3; rel = lin - 96; nb = 16; }
        int fam = task >> 1, stage = task & 1;
        int Co = stage ? H2 : H1;
        int Ci = stage ? H1 : CT;
        const float* w  = A.mw[task];
        const float* g  = A.mg[task];
        ushort* Wb = A.Wmlp + fam * WMLP_FAM + stage * WMLP_B;
        int tot = Co * Ci;
        for (int idx = rel * 256 + t; idx < tot; idx += nb * 256) {
            int o = idx / Ci;
            Wb[idx] = f2b(w[idx] * (g[o] * rs));
        }
        if (rel == 0) {
            const float* bb = A.mb[task];
            const float* be = A.mbe[task];
            float* bp = A.bmlp + fam * BMLP_FAM + stage * BMLP_B;
            for (int o = t; o < Co; o += 256)
                bp[o] = bb[o] * (g[o] * rs) + be[o];
        }
    }
}

// ---------------- conv as bf16 MFMA GEMM over windowed-Gb rows, all slots+convs in one grid ----------------
__global__ __launch_bounds__(256) void k_cmfma(
    const ushort* __restrict__ Gb, const ushort* __restrict__ Wpack,
    const float* __restrict__ bpack, ushort* __restrict__ Xb, int rowBase)
{
    const int kcpm[5] = {128, 224, 224, 288, 288};
    const int offm[5] = {2, 1, 1, 0, 0};
    const int o0m[5]  = {0, 0, 128, 0, 128};
    const int c0m[5]  = {0, 128, 128, 384, 384};   // X column base of conv j
    const int wofm[5] = {PK2_J0, PK2_J1, PK2_J1, PK2_J2, PK2_J2};

    __shared__ ushort Al[128 * 40];
    __shared__ ushort Bl[128 * 40];
    int y = blockIdx.y;
    int Kcp = kcpm[y], off = offm[y], o0 = o0m[y];
    int r0g = rowBase + blockIdx.x * 128;          // global row (slot-major)
    int slot = r0g / SLOTROWS;                     // blocks never straddle slots (21504%128==0)
    const ushort* Wt = Wpack + slot * PK2_SLOT + wofm[y] + (size_t)o0 * Kcp;
    const float*  bp = bpack + slot * CT;
    int p0 = r0g - rowBase;                        // chunk-local row base

    int t = threadIdx.x, lane = t & 63, w = t >> 6;
    int r0 = (w >> 1) * 64, c0w = (w & 1) * 64;

    int row_a = t >> 2, seg = t & 3;
    int rg0 = r0g + row_a, rg1 = rg0 + 64;
    int rr0 = rg0 - slot * SLOTROWS, rr1 = rg1 - slot * SLOTROWS;
    size_t wb0 = (size_t)(rr0 / LO) * GROW + (off + rr0 % LO) * LPAD;
    size_t wb1 = (size_t)(rr1 / LO) * GROW + (off + rr1 % LO) * LPAD;

    f4v acc[4][4];
    #pragma unroll
    for (int m = 0; m < 4; ++m)
        #pragma unroll
        for (int n = 0; n < 4; ++n)
            acc[m][n] = (f4v){0.f, 0.f, 0.f, 0.f};

    int nkt = Kcp >> 5;
    for (int kt = 0; kt < nkt; ++kt) {
        int k0 = kt << 5;
        __syncthreads();
        *(s8v*)&Al[row_a * 40 + seg * 8]        = *(const s8v*)&Gb[wb0 + k0 + seg * 8];
        *(s8v*)&Al[(row_a + 64) * 40 + seg * 8] = *(const s8v*)&Gb[wb1 + k0 + seg * 8];
        *(s8v*)&Bl[row_a * 40 + seg * 8]        = *(const s8v*)&Wt[(size_t)row_a * Kcp + k0 + seg * 8];
        *(s8v*)&Bl[(row_a + 64) * 40 + seg * 8] = *(const s8v*)&Wt[(size_t)(row_a + 64) * Kcp + k0 + seg * 8];
        __syncthreads();
        s8v a[4], b[4];
        #pragma unroll
        for (int m = 0; m < 4; ++m)
            a[m] = *(const s8v*)&Al[(r0 + m * 16 + (lane & 15)) * 40 + (lane >> 4) * 8];
        #pragma unroll
        for (int n = 0; n < 4; ++n)
            b[n] = *(const s8v*)&Bl[(c0w + n * 16 + (lane & 15)) * 40 + (lane >> 4) * 8];
        #pragma unroll
        for (int m = 0; m < 4; ++m)
            #pragma unroll
            for (int n = 0; n < 4; ++n)
                acc[m][n] = __builtin_amdgcn_mfma_f32_16x16x32_bf16(a[m], b[n], acc[m][n], 0, 0, 0);
    }

    int cl = lane & 15, rq = lane >> 4;
    #pragma unroll
    for (int m = 0; m < 4; ++m) {
        #pragma unroll
        for (int n = 0; n < 4; ++n) {
            int oc = c0m[y] + o0 + c0w + n * 16 + cl;
            float bv = bp[oc];
            #pragma unroll
            for (int j = 0; j < 4; ++j) {
                int p = p0 + r0 + m * 16 + rq * 4 + j;
                Xb[(size_t)p * CT + oc] = f2b(fmaxf(acc[m][n][j] + bv, 0.f));
            }
        }
    }
}

// ---------------- bf16 MFMA GEMM, 128x128 tile, BK=32, slot-aware weight family ----------------
template<int OUTB>
__global__ __launch_bounds__(256) void k_mgemm(
    const ushort* __restrict__ Xin, int Cin,
    const ushort* __restrict__ Wbase, const float* __restrict__ bbase,
    int woff, int boff,
    ushort* __restrict__ Yb, float* __restrict__ Yf, int Cout, int rowBase)
{
    __shared__ ushort Al[128 * 40];
    __shared__ ushort Bl[128 * 40];
    int t = threadIdx.x;
    int p0g = rowBase + blockIdx.x * 128;
    int fam = (p0g < SLOTROWS) ? 0 : 1;
    const ushort* Wb = Wbase + (size_t)fam * WMLP_FAM + woff;
    const float*  bp = bbase + fam * BMLP_FAM + boff;
    int p0 = p0g - rowBase, o0 = blockIdx.y * 128;
    int lane = t & 63, w = t >> 6;
    int r0 = (w >> 1) * 64, c0 = (w & 1) * 64;

    f4v acc[4][4];
    #pragma unroll
    for (int m = 0; m < 4; ++m)
        #pragma unroll
        for (int n = 0; n < 4; ++n)
            acc[m][n] = (f4v){0.f, 0.f, 0.f, 0.f};

    int nkt = Cin >> 5;
    for (int kt = 0; kt < nkt; ++kt) {
        int k0 = kt << 5;
        __syncthreads();
        #pragma unroll
        for (int h = 0; h < 2; ++h) {
            int L = t + h * 256;
            int row = L >> 2, seg = L & 3;
            *(s8v*)&Al[row * 40 + seg * 8] =
                *(const s8v*)&Xin[(size_t)(p0 + row) * Cin + k0 + seg * 8];
            *(s8v*)&Bl[row * 40 + seg * 8] =
                *(const s8v*)&Wb[(size_t)(o0 + row) * Cin + k0 + seg * 8];
        }
        __syncthreads();
        s8v a[4], b[4];
        #pragma unroll
        for (int m = 0; m < 4; ++m)
            a[m] = *(const s8v*)&Al[(r0 + m * 16 + (lane & 15)) * 40 + (lane >> 4) * 8];
        #pragma unroll
        for (int n = 0; n < 4; ++n)
            b[n] = *(const s8v*)&Bl[(c0 + n * 16 + (lane & 15)) * 40 + (lane >> 4) * 8];
        #pragma unroll
        for (int m = 0; m < 4; ++m)
            #pragma unroll
            for (int n = 0; n < 4; ++n)
                acc[m][n] = __builtin_amdgcn_mfma_f32_16x16x32_bf16(a[m], b[n], acc[m][n], 0, 0, 0);
    }

    int cl = lane & 15, rq = lane >> 4;
    #pragma unroll
    for (int m = 0; m < 4; ++m) {
        #pragma unroll
        for (int n = 0; n < 4; ++n) {
            int o = o0 + c0 + n * 16 + cl;
            float bv = bp[o];
            #pragma unroll
            for (int j = 0; j < 4; ++j) {
                int p = p0 + r0 + m * 16 + rq * 4 + j;
                float v = fmaxf(acc[m][n][j] + bv, 0.f);
                if (OUTB) {
                    Yb[(size_t)p * Cout + o] = f2b(v);
                } else {
                    Yf[(size_t)p * Cout + o] = v;
                }
            }
        }
    }
}

// ---------------- masked max-pool over i, all slots in chunk ----------------
__global__ __launch_bounds__(128) void k_pool(
    const float* __restrict__ Zc, const int* __restrict__ pep_x,
    float* __restrict__ pool, int rowBase)
{
    int sl = blockIdx.x;                 // chunk-local sample index
    int sg = rowBase / LO + sl;          // global sample-slot index
    int slot = sg / NS, n = sg - slot * NS;
    int c = blockIdx.y * 128 + threadIdx.x;
    float m = -INFINITY;
    for (int i = 0; i < LO; ++i)
        if (pep_x[n * LP + 3 + i] != 0)
            m = fmaxf(m, Zc[(size_t)(sl * LO + i) * H2 + c]);
    pool[(size_t)n * (3 * H2) + slot * H2 + c] = m;
}

// ---------------- attention head per sample ----------------
__global__ __launch_bounds__(256) void k_poolhead(
    const float* __restrict__ pool,
    const float* __restrict__ w_att1, const float* __restrict__ b_att1,
    const float* __restrict__ w_att2, const float* __restrict__ b_att2,
    const float* __restrict__ w_out, const float* __restrict__ b_out,
    float* __restrict__ a_out, float* __restrict__ s2_out)
{
    int n = blockIdx.x, c = threadIdx.x;
    __shared__ float feat_s[H2];
    __shared__ float red[7][H2];
    __shared__ float sc_s[6];

    float mx[3];
    #pragma unroll
    for (int w = 0; w < 3; ++w)
        mx[w] = pool[(size_t)n * (3 * H2) + w * H2 + c];

    float fv = (mx[0] + mx[1] + mx[2]) * (1.f / 3.f);
    feat_s[c] = fv;
    #pragma unroll
    for (int o = 0; o < 2; ++o)
        #pragma unroll
        for (int w = 0; w < 3; ++w)
            red[o * 3 + w][c] = w_out[o * H2 + c] * mx[w];
    __syncthreads();

    float hacc = 0.f;
    for (int cc = 0; cc < H2; ++cc)
        hacc = fmaf(w_att1[(size_t)c * H2 + cc], feat_s[cc], hacc);
    float h = tanhf(hacc + b_att1[c]);
    red[6][c] = h * w_att2[c];
    __syncthreads();

    for (int s = 128; s > 0; s >>= 1) {
        if (c < s) {
            #pragma unroll
            for (int jj = 0; jj < 7; ++jj) red[jj][c] += red[jj][c + s];
        }
        __syncthreads();
    }
    if (c == 0) a_out[n] = red[6][0] + b_att2[0];
    if (c < 6) {
        float x = red[c][0] + b_out[c / 3];
        sc_s[c] = 1.f / (1.f + expf(-x));
    }
    __syncthreads();
    if (c < 2) {
        float half = 0.5f * (sc_s[c * 3 + 0] + sc_s[c * 3 + 1]);
        s2_out[n * 2 + c] = fmaxf(half, sc_s[c * 3 + 2]);   // inverse==1 path
    }
}

// ---------------- bag segment softmax + weighted sum ----------------
__global__ __launch_bounds__(1024) void k_final(
    const float* __restrict__ a_in, const float* __restrict__ s2_in,
    const int* __restrict__ bags, float* __restrict__ out)
{
    __shared__ float a_s[NS], s0_s[NS], s1_s[NS];
    __shared__ int off_s[33];
    int t = threadIdx.x;
    a_s[t]  = a_in[t];
    s0_s[t] = s2_in[t * 2 + 0];
    s1_s[t] = s2_in[t * 2 + 1];
    if (t == 0) {
        off_s[0] = 0;
        for (int g = 0; g < 32; ++g) off_s[g + 1] = off_s[g] + bags[g];
    }
    __syncthreads();
    if (t < 32) {
        int st = off_s[t], en = off_s[t + 1];
        float mxv = -INFINITY;
        for (int n = st; n < en; ++n) mxv = fmaxf(mxv, a_s[n]);
        float se = 0.f;
        for (int n = st; n < en; ++n) se += expf(a_s[n] - mxv);
        float inv = 1.f / se;
        float o0 = 0.f, o1 = 0.f;
        for (int n = st; n < en; ++n) {
            float w = expf(a_s[n] - mxv) * inv;
            o0 += w * s0_s[n];
            o1 += w * s1_s[n];
        }
        out[t * 2 + 0] = fminf(fmaxf(o0, 0.f), 1.f);
        out[t * 2 + 1] = fminf(fmaxf(o1, 0.f), 1.f);
    }
}

extern "C" void kernel_launch(void* const* d_in, const int* in_sizes, int n_in,
                              void* d_out, int out_size, void* d_ws, size_t ws_size,
                              hipStream_t stream) {
    const int* pep_x = (const int*)d_in[0];
    const int* mhc_x = (const int*)d_in[1];
    const int* bags  = (const int*)d_in[4];

    char* wsb = (char*)d_ws;
    // byte-offset workspace layout (all 16B-aligned)
    float*  pool   = (float*) (wsb + 0);          // 3,145,728
    float*  a_buf  = (float*) (wsb + 3145728);    //     4,096
    float*  s2_buf = (float*) (wsb + 3149824);    //     8,192
    ushort* Wpack  = (ushort*)(wsb + 3158016);    //   884,736
    float*  bpack  = (float*) (wsb + 4042752);    //     7,680
    ushort* Wmlp   = (ushort*)(wsb + 4050432);    // 1,835,008
    float*  bmlp   = (float*) (wsb + 5885440);    //     6,144
    ushort* Gb     = (ushort*)(wsb + 5891584);    // 2,211,968
    const size_t XB_B = 8103552;

    // chunking: all 3 slots at once if workspace allows, else 1 slot per chunk
    size_t fullNeed = XB_B + (size_t)ALLROWS * (1280 + 1024 + 1024);
    int chunkSlots = (fullNeed <= ws_size) ? 3 : 1;
    int RC = chunkSlots * SLOTROWS;               // rows per chunk
    ushort* Xb = (ushort*)(wsb + XB_B);                       // RC*640 bf16
    ushort* Yb = (ushort*)((char*)Xb + (size_t)RC * 1280);    // RC*512 bf16
    float*  Zc = (float*) ((char*)Yb + (size_t)RC * 1024);    // RC*256 f32

    PrepArgs pa;
    pa.pep_x = pep_x; pa.mhc_x = mhc_x;
    pa.emb_pep = (const float*)d_in[6];
    pa.emb_mhc = (const float*)d_in[7];
    for (int j = 0; j < 3; ++j) {
        pa.cw[0][j]  = (const float*)d_in[8 + 4 * j];
        pa.cb[0][j]  = (const float*)d_in[9 + 4 * j];
        pa.cg[0][j]  = (const float*)d_in[10 + 4 * j];
        pa.cbe[0][j] = (const float*)d_in[11 + 4 * j];
        pa.cw[1][j]  = (const float*)d_in[20 + 4 * j];
        pa.cb[1][j]  = (const float*)d_in[21 + 4 * j];
        pa.cg[1][j]  = (const float*)d_in[22 + 4 * j];
        pa.cbe[1][j] = (const float*)d_in[23 + 4 * j];
    }
    // mlp tasks: {fam0 A (32..35), fam0 B (36..39), fam1 A (40..43), fam1 B (44..47)}
    for (int task = 0; task < 4; ++task) {
        int base = 32 + task * 4;
        pa.mw[task]  = (const float*)d_in[base + 0];
        pa.mb[task]  = (const float*)d_in[base + 1];
        pa.mg[task]  = (const float*)d_in[base + 2];
        pa.mbe[task] = (const float*)d_in[base + 3];
    }
    pa.Gb = Gb; pa.Wpack = Wpack; pa.bpack = bpack; pa.Wmlp = Wmlp; pa.bmlp = bmlp;

    k_prep<<<dim3(NS + 144 + 112), dim3(256), 0, stream>>>(pa);

    for (int rowBase = 0; rowBase < ALLROWS; rowBase += RC) {
        int nRB = RC / 128;
        k_cmfma<<<dim3(nRB, 5), dim3(256), 0, stream>>>(Gb, Wpack, bpack, Xb, rowBase);
        k_mgemm<1><<<dim3(nRB, H1 / 128), dim3(256), 0, stream>>>(
            Xb, CT, Wmlp, bmlp, 0, 0, Yb, nullptr, H1, rowBase);
        k_mgemm<0><<<dim3(nRB, H2 / 128), dim3(256), 0, stream>>>(
            Yb, H1, Wmlp, bmlp, WMLP_B, BMLP_B, nullptr, Zc, H2, rowBase);
        k_pool<<<dim3(RC / LO, H2 / 128), dim3(128), 0, stream>>>(
            Zc, pep_x, pool, rowBase);
    }

    k_poolhead<<<dim3(NS), dim3(256), 0, stream>>>(
        pool,
        (const float*)d_in[48], (const float*)d_in[49], (const float*)d_in[50], (const float*)d_in[51],
        (const float*)d_in[52], (const float*)d_in[53],
        a_buf, s2_buf);

    k_final<<<dim3(1), dim3(1024), 0, stream>>>(a_buf, s2_buf, bags, (float*)d_out);
}

// Round 10
// 207.087 us; speedup vs baseline: 12.8058x; 1.1164x over previous
//
#include <hip/hip_runtime.h>
#include <hip/hip_bf16.h>
#include <math.h>

#define NS   1024
#define LP   27
#define MMH  34
#define EE   16
#define LO   21
#define CT   640
#define H1   512
#define H2   256
#define LPAD 40
#define GROW (LP*LPAD)      // 1080 bf16 els per sample
#define SLOTROWS (NS*LO)    // 21504
#define ALLROWS  (3*SLOTROWS)

typedef __attribute__((ext_vector_type(8))) short  s8v;
typedef __attribute__((ext_vector_type(4))) float  f4v;

// packed conv-weight geometry: col = k*40 + m, Kcp = K*40 padded to mult-32
#define PK2_SLOT 147456     // 128*128 + 256*224 + 256*288
#define PK2_J0   0
#define PK2_J1   16384
#define PK2_J2   73728
// MLP pack offsets
#define WMLP_FAM 458752     // 512*640 + 256*512
#define WMLP_B   327680     // 512*640
#define BMLP_FAM 768
#define BMLP_B   512

__device__ __forceinline__ ushort f2b(float v) {
    __hip_bfloat16 hb = __float2bfloat16(v);
    return *reinterpret_cast<ushort*>(&hb);
}

__device__ __forceinline__ float pe_val(int pos, int e) {
    int j = e >> 1;
    float div = expf(-1.1512925464970229f * (float)j);  // 10000^(-j/8)
    float ang = (float)pos * div;
    return (e & 1) ? cosf(ang) : sinf(ang);
}

// ---------------- fused prep: embG | conv pack | mlp pack | pool zero ----------------
struct PrepArgs {
    const int* pep_x; const int* mhc_x;
    const float* emb_pep; const float* emb_mhc;
    const float* cw[2][3]; const float* cb[2][3]; const float* cg[2][3]; const float* cbe[2][3];
    const float* mw[4]; const float* mb[4]; const float* mg[4]; const float* mbe[4];
    ushort* Gb; ushort* Wpack; float* bpack; ushort* Wmlp; float* bmlp; int* poolI;
};

__global__ __launch_bounds__(256) void k_prep(PrepArgs A) {
    int b = blockIdx.x, t = threadIdx.x;
    float rs = rsqrtf(1.0f + 1e-5f);
    if (b < NS) {
        __shared__ float ps[LP * 17];
        __shared__ float ms[MMH * 17];
        int n = b;
        for (int idx = t; idx < LP * EE; idx += 256) {
            int l = idx >> 4, e = idx & 15;
            float v = A.emb_pep[A.pep_x[n * LP + l] * EE + e];
            if (l >= 3 && l < 24) v += pe_val(l - 3, e);
            ps[l * 17 + e] = v;
        }
        for (int idx = t; idx < MMH * EE; idx += 256) {
            int m = idx >> 4, e = idx & 15;
            ms[m * 17 + e] = A.emb_mhc[A.mhc_x[n * MMH + m] * EE + e] + pe_val(m, e);
        }
        __syncthreads();
        for (int idx = t; idx < GROW; idx += 256) {
            int l = idx / LPAD, m = idx - l * LPAD;
            float s = 0.f;
            if (m < MMH) {
                #pragma unroll
                for (int e = 0; e < EE; ++e) s = fmaf(ps[l * 17 + e], ms[m * 17 + e], s);
            }
            A.Gb[(size_t)n * GROW + idx] = f2b(s);
        }
        if (n == 0 && t < 64) A.Gb[(size_t)NS * GROW + t] = 0;
    } else if (b < NS + 144) {
        const int KS_[3]  = {3, 5, 7};
        const int KCP_[3] = {128, 224, 288};
        const int NC_[3]  = {128, 256, 256};
        const int pkoff[3] = {PK2_J0, PK2_J1, PK2_J2};
        const int bpoff[3] = {0, 128, 384};
        int lin = b - NS;
        int s = lin / 48, rem = lin - s * 48, j = rem >> 4, z = rem & 15;
        int K = KS_[j], Kcp = KCP_[j], nc = NC_[j];
        int fam = (s == 0) ? 0 : 1;
        const float* w  = A.cw[fam][j];
        const float* g  = A.cg[fam][j];
        ushort* Wp = A.Wpack + s * PK2_SLOT + pkoff[j];
        int tot = nc * Kcp;
        for (int idx = z * 256 + t; idx < tot; idx += 16 * 256) {
            int c = idx / Kcp, col = idx - c * Kcp;
            int k = col / LPAD, m = col - k * LPAD;
            float v = 0.f;
            if (k < K && m < MMH) {
                int kk = (s == 2) ? (K - 1 - k) : k;
                v = w[((size_t)c * K + kk) * MMH + m] * (g[c] * rs);
            }
            Wp[idx] = f2b(v);
        }
        if (z == 0) {
            const float* bb = A.cb[fam][j];
            const float* be = A.cbe[fam][j];
            float* bp = A.bpack + s * CT + bpoff[j];
            for (int c = t; c < nc; c += 256)
                bp[c] = bb[c] * (g[c] * rs) + be[c];
        }
    } else if (b < NS + 144 + 112) {
        int lin = b - NS - 144;
        int task, rel, nb;
        if (lin < 40)      { task = 0; rel = lin;      nb = 40; }
        else if (lin < 56) { task = 1; rel = lin - 40; nb = 16; }
        else if (lin < 96) { task = 2; rel = lin - 56; nb = 40; }
        else               { task = 3; rel = lin - 96; nb = 16; }
        int fam = task >> 1, stage = task & 1;
        int Co = stage ? H2 : H1;
        int Ci = stage ? H1 : CT;
        const float* w  = A.mw[task];
        const float* g  = A.mg[task];
        ushort* Wb = A.Wmlp + fam * WMLP_FAM + stage * WMLP_B;
        int tot = Co * Ci;
        for (int idx = rel * 256 + t; idx < tot; idx += nb * 256) {
            int o = idx / Ci;
            Wb[idx] = f2b(w[idx] * (g[o] * rs));
        }
        if (rel == 0) {
            const float* bb = A.mb[task];
            const float* be = A.mbe[task];
            float* bp = A.bmlp + fam * BMLP_FAM + stage * BMLP_B;
            for (int o = t; o < Co; o += 256)
                bp[o] = bb[o] * (g[o] * rs) + be[o];
        }
    } else {
        // pool zero: 96 blocks * 8192 ints = 786432
        int base = (b - NS - 144 - 112) * 8192;
        #pragma unroll
        for (int q = 0; q < 32; ++q)
            A.poolI[base + q * 256 + t] = 0;
    }
}

// ---------------- conv as bf16 MFMA GEMM, LDS-staged coalesced epilogue ----------------
__global__ __launch_bounds__(256) void k_cmfma(
    const ushort* __restrict__ Gb, const ushort* __restrict__ Wpack,
    const float* __restrict__ bpack, ushort* __restrict__ Xb, int rowBase)
{
    const int kcpm[5] = {128, 224, 224, 288, 288};
    const int offm[5] = {2, 1, 1, 0, 0};
    const int o0m[5]  = {0, 0, 128, 0, 128};
    const int c0m[5]  = {0, 128, 128, 384, 384};
    const int wofm[5] = {PK2_J0, PK2_J1, PK2_J1, PK2_J2, PK2_J2};

    __shared__ ushort smC[17408];           // staging 10240 | epi 17408 (aliased)
    ushort* Al = smC;
    ushort* Bl = smC + 5120;
    int y = blockIdx.x;
    int Kcp = kcpm[y], off = offm[y], o0 = o0m[y];
    int c0X = c0m[y] + o0;
    int r0g = rowBase + blockIdx.y * 128;
    int slot = r0g / SLOTROWS;
    const ushort* Wt = Wpack + slot * PK2_SLOT + wofm[y] + (size_t)o0 * Kcp;
    const float*  bp = bpack + slot * CT;
    int p0 = blockIdx.y * 128;

    int t = threadIdx.x, lane = t & 63, w = t >> 6;
    int r0 = (w >> 1) * 64, c0w = (w & 1) * 64;

    int row_a = t >> 2, seg = t & 3;
    int rg0 = r0g + row_a, rg1 = rg0 + 64;
    int rr0 = rg0 - slot * SLOTROWS, rr1 = rg1 - slot * SLOTROWS;
    size_t wb0 = (size_t)(rr0 / LO) * GROW + (off + rr0 % LO) * LPAD;
    size_t wb1 = (size_t)(rr1 / LO) * GROW + (off + rr1 % LO) * LPAD;

    f4v acc[4][4];
    #pragma unroll
    for (int m = 0; m < 4; ++m)
        #pragma unroll
        for (int n = 0; n < 4; ++n)
            acc[m][n] = (f4v){0.f, 0.f, 0.f, 0.f};

    int nkt = Kcp >> 5;
    for (int kt = 0; kt < nkt; ++kt) {
        int k0 = kt << 5;
        __syncthreads();
        *(s8v*)&Al[row_a * 40 + seg * 8]        = *(const s8v*)&Gb[wb0 + k0 + seg * 8];
        *(s8v*)&Al[(row_a + 64) * 40 + seg * 8] = *(const s8v*)&Gb[wb1 + k0 + seg * 8];
        *(s8v*)&Bl[row_a * 40 + seg * 8]        = *(const s8v*)&Wt[(size_t)row_a * Kcp + k0 + seg * 8];
        *(s8v*)&Bl[(row_a + 64) * 40 + seg * 8] = *(const s8v*)&Wt[(size_t)(row_a + 64) * Kcp + k0 + seg * 8];
        __syncthreads();
        s8v a[4], b[4];
        #pragma unroll
        for (int m = 0; m < 4; ++m)
            a[m] = *(const s8v*)&Al[(r0 + m * 16 + (lane & 15)) * 40 + (lane >> 4) * 8];
        #pragma unroll
        for (int n = 0; n < 4; ++n)
            b[n] = *(const s8v*)&Bl[(c0w + n * 16 + (lane & 15)) * 40 + (lane >> 4) * 8];
        #pragma unroll
        for (int m = 0; m < 4; ++m)
            #pragma unroll
            for (int n = 0; n < 4; ++n)
                acc[m][n] = __builtin_amdgcn_mfma_f32_16x16x32_bf16(a[m], b[n], acc[m][n], 0, 0, 0);
    }

    // epilogue: stage bf16 tile in LDS, then coalesced stores
    int cl = lane & 15, rq = lane >> 4;
    __syncthreads();
    #pragma unroll
    for (int m = 0; m < 4; ++m)
        #pragma unroll
        for (int n = 0; n < 4; ++n) {
            int ocr = c0w + n * 16 + cl;
            float bv = bp[c0X + ocr];
            #pragma unroll
            for (int j = 0; j < 4; ++j)
                smC[(r0 + m * 16 + rq * 4 + j) * 136 + ocr] = f2b(fmaxf(acc[m][n][j] + bv, 0.f));
        }
    __syncthreads();
    int ci = t & 15;
    #pragma unroll
    for (int it = 0; it < 8; ++it) {
        int row = (t >> 4) + it * 16;
        *(s8v*)&Xb[(size_t)(p0 + row) * CT + c0X + ci * 8] = *(const s8v*)&smC[row * 136 + ci * 8];
    }
}

// ---------------- MLP stage A: bf16 MFMA GEMM, BK=64, LDS-staged bf16 epilogue ----------------
__global__ __launch_bounds__(256) void k_mgemmA(
    const ushort* __restrict__ Xin,
    const ushort* __restrict__ Wbase, const float* __restrict__ bbase,
    ushort* __restrict__ Yb, int rowBase)
{
    __shared__ ushort smA[18432];          // staging 2*9216 | epi 17408 (aliased)
    ushort* Al = smA;
    ushort* Bl = smA + 9216;
    int t = threadIdx.x;
    int o0 = blockIdx.x * 128;
    int p0 = blockIdx.y * 128;
    int g0 = rowBase + p0;
    int fam = (g0 < SLOTROWS) ? 0 : 1;
    const ushort* Wb = Wbase + (size_t)fam * WMLP_FAM;
    const float*  bp = bbase + fam * BMLP_FAM;
    int lane = t & 63, w = t >> 6;
    int r0 = (w >> 1) * 64, c0 = (w & 1) * 64;

    f4v acc[4][4];
    #pragma unroll
    for (int m = 0; m < 4; ++m)
        #pragma unroll
        for (int n = 0; n < 4; ++n)
            acc[m][n] = (f4v){0.f, 0.f, 0.f, 0.f};

    for (int kt = 0; kt < CT / 64; ++kt) {
        int k0 = kt << 6;
        __syncthreads();
        #pragma unroll
        for (int it = 0; it < 4; ++it) {
            int idx = t + it * 256;
            int row = idx >> 3, sg = idx & 7;
            *(s8v*)&Al[row * 72 + sg * 8] = *(const s8v*)&Xin[(size_t)(p0 + row) * CT + k0 + sg * 8];
            *(s8v*)&Bl[row * 72 + sg * 8] = *(const s8v*)&Wb[(size_t)(o0 + row) * CT + k0 + sg * 8];
        }
        __syncthreads();
        #pragma unroll
        for (int ks = 0; ks < 2; ++ks) {
            int kc = ks * 32 + (lane >> 4) * 8;
            s8v a[4], b[4];
            #pragma unroll
            for (int m = 0; m < 4; ++m)
                a[m] = *(const s8v*)&Al[(r0 + m * 16 + (lane & 15)) * 72 + kc];
            #pragma unroll
            for (int n = 0; n < 4; ++n)
                b[n] = *(const s8v*)&Bl[(c0 + n * 16 + (lane & 15)) * 72 + kc];
            #pragma unroll
            for (int m = 0; m < 4; ++m)
                #pragma unroll
                for (int n = 0; n < 4; ++n)
                    acc[m][n] = __builtin_amdgcn_mfma_f32_16x16x32_bf16(a[m], b[n], acc[m][n], 0, 0, 0);
        }
    }

    int cl = lane & 15, rq = lane >> 4;
    __syncthreads();
    #pragma unroll
    for (int m = 0; m < 4; ++m)
        #pragma unroll
        for (int n = 0; n < 4; ++n) {
            int ocr = c0 + n * 16 + cl;
            float bv = bp[o0 + ocr];
            #pragma unroll
            for (int j = 0; j < 4; ++j)
                smA[(r0 + m * 16 + rq * 4 + j) * 136 + ocr] = f2b(fmaxf(acc[m][n][j] + bv, 0.f));
        }
    __syncthreads();
    int ci = t & 15;
    #pragma unroll
    for (int it = 0; it < 8; ++it) {
        int row = (t >> 4) + it * 16;
        *(s8v*)&Yb[(size_t)(p0 + row) * H1 + o0 + ci * 8] = *(const s8v*)&smA[row * 136 + ci * 8];
    }
}

// ---------------- MLP stage B fused with masked max-pool (atomicMax, relu>=0) ----------------
__global__ __launch_bounds__(256) void k_mgemmB(
    const ushort* __restrict__ Yin,
    const ushort* __restrict__ Wbase, const float* __restrict__ bbase,
    const int* __restrict__ pep_x, int* __restrict__ poolI, int rowBase)
{
    __shared__ float zbuf[128 * 129];      // 66048 B; staging aliased at front
    __shared__ int mvalid[128];
    ushort* Al = (ushort*)zbuf;
    ushort* Bl = Al + 9216;
    int t = threadIdx.x;
    int o0 = blockIdx.x * 128;
    int p0 = blockIdx.y * 128;
    int g0 = rowBase + p0;
    int slot = g0 / SLOTROWS;
    int gs0 = g0 - slot * SLOTROWS;
    int fam = (slot == 0) ? 0 : 1;
    const ushort* Wb = Wbase + (size_t)fam * WMLP_FAM + WMLP_B;
    const float*  bp = bbase + fam * BMLP_FAM + BMLP_B;
    int lane = t & 63, w = t >> 6;
    int r0 = (w >> 1) * 64, c0 = (w & 1) * 64;

    f4v acc[4][4];
    #pragma unroll
    for (int m = 0; m < 4; ++m)
        #pragma unroll
        for (int n = 0; n < 4; ++n)
            acc[m][n] = (f4v){0.f, 0.f, 0.f, 0.f};

    for (int kt = 0; kt < H1 / 64; ++kt) {
        int k0 = kt << 6;
        __syncthreads();
        #pragma unroll
        for (int it = 0; it < 4; ++it) {
            int idx = t + it * 256;
            int row = idx >> 3, sg = idx & 7;
            *(s8v*)&Al[row * 72 + sg * 8] = *(const s8v*)&Yin[(size_t)(p0 + row) * H1 + k0 + sg * 8];
            *(s8v*)&Bl[row * 72 + sg * 8] = *(const s8v*)&Wb[(size_t)(o0 + row) * H1 + k0 + sg * 8];
        }
        __syncthreads();
        #pragma unroll
        for (int ks = 0; ks < 2; ++ks) {
            int kc = ks * 32 + (lane >> 4) * 8;
            s8v a[4], b[4];
            #pragma unroll
            for (int m = 0; m < 4; ++m)
                a[m] = *(const s8v*)&Al[(r0 + m * 16 + (lane & 15)) * 72 + kc];
            #pragma unroll
            for (int n = 0; n < 4; ++n)
                b[n] = *(const s8v*)&Bl[(c0 + n * 16 + (lane & 15)) * 72 + kc];
            #pragma unroll
            for (int m = 0; m < 4; ++m)
                #pragma unroll
                for (int n = 0; n < 4; ++n)
                    acc[m][n] = __builtin_amdgcn_mfma_f32_16x16x32_bf16(a[m], b[n], acc[m][n], 0, 0, 0);
        }
    }

    int cl = lane & 15, rq = lane >> 4;
    __syncthreads();
    if (t < 128) {
        int gs = gs0 + t;
        int n = gs / LO, i = gs - n * LO;
        mvalid[t] = (pep_x[n * LP + 3 + i] != 0) ? 1 : 0;
    }
    #pragma unroll
    for (int m = 0; m < 4; ++m)
        #pragma unroll
        for (int n = 0; n < 4; ++n) {
            int ocr = c0 + n * 16 + cl;
            float bv = bp[o0 + ocr];
            #pragma unroll
            for (int j = 0; j < 4; ++j)
                zbuf[(r0 + m * 16 + rq * 4 + j) * 129 + ocr] = fmaxf(acc[m][n][j] + bv, 0.f);
        }
    __syncthreads();

    // per-column segmented max over samples (21-row periods), atomicMax into pool
    int col = t & 127, half = t >> 7;
    int colg = o0 + col;
    int rs = half * 64;
    int gs = gs0 + rs;
    int n = gs / LO, i = gs - n * LO;
    float cur = -1.f;
    for (int r = rs; r < rs + 64; ++r) {
        if (mvalid[r]) cur = fmaxf(cur, zbuf[r * 129 + col]);
        if (++i == LO) {
            if (cur >= 0.f)
                atomicMax(&poolI[n * (3 * H2) + slot * H2 + colg], __float_as_int(cur));
            cur = -1.f; ++n; i = 0;
        }
    }
    if (cur >= 0.f)
        atomicMax(&poolI[n * (3 * H2) + slot * H2 + colg], __float_as_int(cur));
}

// ---------------- attention head per sample ----------------
__global__ __launch_bounds__(256) void k_poolhead(
    const float* __restrict__ pool,
    const float* __restrict__ w_att1, const float* __restrict__ b_att1,
    const float* __restrict__ w_att2, const float* __restrict__ b_att2,
    const float* __restrict__ w_out, const float* __restrict__ b_out,
    float* __restrict__ a_out, float* __restrict__ s2_out)
{
    int n = blockIdx.x, c = threadIdx.x;
    __shared__ float feat_s[H2];
    __shared__ float red[7][H2];
    __shared__ float sc_s[6];

    float mx[3];
    #pragma unroll
    for (int w = 0; w < 3; ++w)
        mx[w] = pool[(size_t)n * (3 * H2) + w * H2 + c];

    float fv = (mx[0] + mx[1] + mx[2]) * (1.f / 3.f);
    feat_s[c] = fv;
    #pragma unroll
    for (int o = 0; o < 2; ++o)
        #pragma unroll
        for (int w = 0; w < 3; ++w)
            red[o * 3 + w][c] = w_out[o * H2 + c] * mx[w];
    __syncthreads();

    float hacc = 0.f;
    for (int cc = 0; cc < H2; ++cc)
        hacc = fmaf(w_att1[(size_t)c * H2 + cc], feat_s[cc], hacc);
    float h = tanhf(hacc + b_att1[c]);
    red[6][c] = h * w_att2[c];
    __syncthreads();

    for (int s = 128; s > 0; s >>= 1) {
        if (c < s) {
            #pragma unroll
            for (int jj = 0; jj < 7; ++jj) red[jj][c] += red[jj][c + s];
        }
        __syncthreads();
    }
    if (c == 0) a_out[n] = red[6][0] + b_att2[0];
    if (c < 6) {
        float x = red[c][0] + b_out[c / 3];
        sc_s[c] = 1.f / (1.f + expf(-x));
    }
    __syncthreads();
    if (c < 2) {
        float half = 0.5f * (sc_s[c * 3 + 0] + sc_s[c * 3 + 1]);
        s2_out[n * 2 + c] = fmaxf(half, sc_s[c * 3 + 2]);   // inverse==1 path
    }
}

// ---------------- bag segment softmax + weighted sum ----------------
__global__ __launch_bounds__(1024) void k_final(
    const float* __restrict__ a_in, const float* __restrict__ s2_in,
    const int* __restrict__ bags, float* __restrict__ out)
{
    __shared__ float a_s[NS], s0_s[NS], s1_s[NS];
    __shared__ int off_s[33];
    int t = threadIdx.x;
    a_s[t]  = a_in[t];
    s0_s[t] = s2_in[t * 2 + 0];
    s1_s[t] = s2_in[t * 2 + 1];
    if (t == 0) {
        off_s[0] = 0;
        for (int g = 0; g < 32; ++g) off_s[g + 1] = off_s[g] + bags[g];
    }
    __syncthreads();
    if (t < 32) {
        int st = off_s[t], en = off_s[t + 1];
        float mxv = -INFINITY;
        for (int n = st; n < en; ++n) mxv = fmaxf(mxv, a_s[n]);
        float se = 0.f;
        for (int n = st; n < en; ++n) se += expf(a_s[n] - mxv);
        float inv = 1.f / se;
        float o0 = 0.f, o1 = 0.f;
        for (int n = st; n < en; ++n) {
            float w = expf(a_s[n] - mxv) * inv;
            o0 += w * s0_s[n];
            o1 += w * s1_s[n];
        }
        out[t * 2 + 0] = fminf(fmaxf(o0, 0.f), 1.f);
        out[t * 2 + 1] = fminf(fmaxf(o1, 0.f), 1.f);
    }
}

extern "C" void kernel_launch(void* const* d_in, const int* in_sizes, int n_in,
                              void* d_out, int out_size, void* d_ws, size_t ws_size,
                              hipStream_t stream) {
    const int* pep_x = (const int*)d_in[0];
    const int* mhc_x = (const int*)d_in[1];
    const int* bags  = (const int*)d_in[4];

    char* wsb = (char*)d_ws;
    float*  pool   = (float*) (wsb + 0);          // 3,145,728 (stored as int bits)
    int*    poolI  = (int*)   (wsb + 0);
    float*  a_buf  = (float*) (wsb + 3145728);
    float*  s2_buf = (float*) (wsb + 3149824);
    ushort* Wpack  = (ushort*)(wsb + 3158016);
    float*  bpack  = (float*) (wsb + 4042752);
    ushort* Wmlp   = (ushort*)(wsb + 4050432);
    float*  bmlp   = (float*) (wsb + 5885440);
    ushort* Gb     = (ushort*)(wsb + 5891584);
    const size_t XB_B = 8103552;

    size_t fullNeed = XB_B + (size_t)ALLROWS * (1280 + 1024);
    int chunkSlots = (fullNeed <= ws_size) ? 3 : 1;
    int RC = chunkSlots * SLOTROWS;
    ushort* Xb = (ushort*)(wsb + XB_B);                       // RC*640 bf16
    ushort* Yb = (ushort*)((char*)Xb + (size_t)RC * 1280);    // RC*512 bf16

    PrepArgs pa;
    pa.pep_x = pep_x; pa.mhc_x = mhc_x;
    pa.emb_pep = (const float*)d_in[6];
    pa.emb_mhc = (const float*)d_in[7];
    for (int j = 0; j < 3; ++j) {
        pa.cw[0][j]  = (const float*)d_in[8 + 4 * j];
        pa.cb[0][j]  = (const float*)d_in[9 + 4 * j];
        pa.cg[0][j]  = (const float*)d_in[10 + 4 * j];
        pa.cbe[0][j] = (const float*)d_in[11 + 4 * j];
        pa.cw[1][j]  = (const float*)d_in[20 + 4 * j];
        pa.cb[1][j]  = (const float*)d_in[21 + 4 * j];
        pa.cg[1][j]  = (const float*)d_in[22 + 4 * j];
        pa.cbe[1][j] = (const float*)d_in[23 + 4 * j];
    }
    for (int task = 0; task < 4; ++task) {
        int base = 32 + task * 4;
        pa.mw[task]  = (const float*)d_in[base + 0];
        pa.mb[task]  = (const float*)d_in[base + 1];
        pa.mg[task]  = (const float*)d_in[base + 2];
        pa.mbe[task] = (const float*)d_in[base + 3];
    }
    pa.Gb = Gb; pa.Wpack = Wpack; pa.bpack = bpack; pa.Wmlp = Wmlp; pa.bmlp = bmlp;
    pa.poolI = poolI;

    k_prep<<<dim3(NS + 144 + 112 + 96), dim3(256), 0, stream>>>(pa);

    for (int rowBase = 0; rowBase < ALLROWS; rowBase += RC) {
        int nRB = RC / 128;
        k_cmfma<<<dim3(5, nRB), dim3(256), 0, stream>>>(Gb, Wpack, bpack, Xb, rowBase);
        k_mgemmA<<<dim3(H1 / 128, nRB), dim3(256), 0, stream>>>(Xb, Wmlp, bmlp, Yb, rowBase);
        k_mgemmB<<<dim3(H2 / 128, nRB), dim3(256), 0, stream>>>(Yb, Wmlp, bmlp, pep_x, poolI, rowBase);
    }

    k_poolhead<<<dim3(NS), dim3(256), 0, stream>>>(
        pool,
        (const float*)d_in[48], (const float*)d_in[49], (const float*)d_in[50], (const float*)d_in[51],
        (const float*)d_in[52], (const float*)d_in[53],
        a_buf, s2_buf);

    k_final<<<dim3(1), dim3(1024), 0, stream>>>(a_buf, s2_buf, bags, (float*)d_out);
}

// Round 12
// 194.949 us; speedup vs baseline: 13.6030x; 1.0623x over previous
//
#include <hip/hip_runtime.h>
#include <hip/hip_bf16.h>
#include <math.h>

#define NS   1024
#define LP   27
#define MMH  34
#define EE   16
#define LO   21
#define CT   640
#define H1   512
#define H2   256
#define LPAD 40
#define GROW (LP*LPAD)      // 1080 bf16 els per sample
#define SLOTROWS (NS*LO)    // 21504
#define ALLROWS  (3*SLOTROWS)

typedef __attribute__((ext_vector_type(8))) short  s8v;
typedef __attribute__((ext_vector_type(4))) float  f4v;

// packed conv-weight geometry: col = k*40 + m, Kcp = K*40 padded to mult-32
#define PK2_SLOT 147456     // 128*128 + 256*224 + 256*288
#define PK2_J0   0
#define PK2_J1   16384
#define PK2_J2   73728
// MLP pack offsets
#define WMLP_FAM 458752     // 512*640 + 256*512
#define WMLP_B   327680     // 512*640
#define BMLP_FAM 768
#define BMLP_B   512

__device__ __forceinline__ ushort f2b(float v) {
    __hip_bfloat16 hb = __float2bfloat16(v);
    return *reinterpret_cast<ushort*>(&hb);
}

__device__ __forceinline__ float pe_val(int pos, int e) {
    int j = e >> 1;
    float div = expf(-1.1512925464970229f * (float)j);  // 10000^(-j/8)
    float ang = (float)pos * div;
    return (e & 1) ? cosf(ang) : sinf(ang);
}

// XCD-aware bijective swizzle of the flat workgroup id (T1; requires nwg%8==0)
__device__ __forceinline__ int xcd_swz() {
    int fid = blockIdx.y * gridDim.x + blockIdx.x;
    int nwg = gridDim.x * gridDim.y;
    int cpx = nwg >> 3;
    return (fid & 7) * cpx + (fid >> 3);
}

// ---------------- fused prep: embG | conv pack | mlp pack | pool zero ----------------
struct PrepArgs {
    const int* pep_x; const int* mhc_x;
    const float* emb_pep; const float* emb_mhc;
    const float* cw[2][3]; const float* cb[2][3]; const float* cg[2][3]; const float* cbe[2][3];
    const float* mw[4]; const float* mb[4]; const float* mg[4]; const float* mbe[4];
    ushort* Gb; ushort* Wpack; float* bpack; ushort* Wmlp; float* bmlp; int* poolI;
};

__global__ __launch_bounds__(256) void k_prep(PrepArgs A) {
    int b = blockIdx.x, t = threadIdx.x;
    float rs = rsqrtf(1.0f + 1e-5f);
    if (b < NS) {
        __shared__ float ps[LP * 17];
        __shared__ float ms[MMH * 17];
        int n = b;
        for (int idx = t; idx < LP * EE; idx += 256) {
            int l = idx >> 4, e = idx & 15;
            float v = A.emb_pep[A.pep_x[n * LP + l] * EE + e];
            if (l >= 3 && l < 24) v += pe_val(l - 3, e);
            ps[l * 17 + e] = v;
        }
        for (int idx = t; idx < MMH * EE; idx += 256) {
            int m = idx >> 4, e = idx & 15;
            ms[m * 17 + e] = A.emb_mhc[A.mhc_x[n * MMH + m] * EE + e] + pe_val(m, e);
        }
        __syncthreads();
        for (int idx = t; idx < GROW; idx += 256) {
            int l = idx / LPAD, m = idx - l * LPAD;
            float s = 0.f;
            if (m < MMH) {
                #pragma unroll
                for (int e = 0; e < EE; ++e) s = fmaf(ps[l * 17 + e], ms[m * 17 + e], s);
            }
            A.Gb[(size_t)n * GROW + idx] = f2b(s);
        }
        if (n == 0 && t < 64) A.Gb[(size_t)NS * GROW + t] = 0;
    } else if (b < NS + 144) {
        const int KS_[3]  = {3, 5, 7};
        const int KCP_[3] = {128, 224, 288};
        const int NC_[3]  = {128, 256, 256};
        const int pkoff[3] = {PK2_J0, PK2_J1, PK2_J2};
        const int bpoff[3] = {0, 128, 384};
        int lin = b - NS;
        int s = lin / 48, rem = lin - s * 48, j = rem >> 4, z = rem & 15;
        int K = KS_[j], Kcp = KCP_[j], nc = NC_[j];
        int fam = (s == 0) ? 0 : 1;
        const float* w  = A.cw[fam][j];
        const float* g  = A.cg[fam][j];
        ushort* Wp = A.Wpack + s * PK2_SLOT + pkoff[j];
        int tot = nc * Kcp;
        for (int idx = z * 256 + t; idx < tot; idx += 16 * 256) {
            int c = idx / Kcp, col = idx - c * Kcp;
            int k = col / LPAD, m = col - k * LPAD;
            float v = 0.f;
            if (k < K && m < MMH) {
                int kk = (s == 2) ? (K - 1 - k) : k;
                v = w[((size_t)c * K + kk) * MMH + m] * (g[c] * rs);
            }
            Wp[idx] = f2b(v);
        }
        if (z == 0) {
            const float* bb = A.cb[fam][j];
            const float* be = A.cbe[fam][j];
            float* bp = A.bpack + s * CT + bpoff[j];
            for (int c = t; c < nc; c += 256)
                bp[c] = bb[c] * (g[c] * rs) + be[c];
        }
    } else if (b < NS + 144 + 112) {
        int lin = b - NS - 144;
        int task, rel, nb;
        if (lin < 40)      { task = 0; rel = lin;      nb = 40; }
        else if (lin < 56) { task = 1; rel = lin - 40; nb = 16; }
        else if (lin < 96) { task = 2; rel = lin - 56; nb = 40; }
        else               { task = 3; rel = lin - 96; nb = 16; }
        int fam = task >> 1, stage = task & 1;
        int Co = stage ? H2 : H1;
        int Ci = stage ? H1 : CT;
        const float* w  = A.mw[task];
        const float* g  = A.mg[task];
        ushort* Wb = A.Wmlp + fam * WMLP_FAM + stage * WMLP_B;
        int tot = Co * Ci;
        for (int idx = rel * 256 + t; idx < tot; idx += nb * 256) {
            int o = idx / Ci;
            Wb[idx] = f2b(w[idx] * (g[o] * rs));
        }
        if (rel == 0) {
            const float* bb = A.mb[task];
            const float* be = A.mbe[task];
            float* bp = A.bmlp + fam * BMLP_FAM + stage * BMLP_B;
            for (int o = t; o < Co; o += 256)
                bp[o] = bb[o] * (g[o] * rs) + be[o];
        }
    } else {
        int base = (b - NS - 144 - 112) * 8192;
        #pragma unroll
        for (int q = 0; q < 32; ++q)
            A.poolI[base + q * 256 + t] = 0;
    }
}

// ---------------- conv as bf16 MFMA GEMM, XCD-swizzled, LDS-staged epilogue ----------------
__global__ __launch_bounds__(256) void k_cmfma(
    const ushort* __restrict__ Gb, const ushort* __restrict__ Wpack,
    const float* __restrict__ bpack, ushort* __restrict__ Xb, int rowBase)
{
    const int kcpm[5] = {128, 224, 224, 288, 288};
    const int offm[5] = {2, 1, 1, 0, 0};
    const int o0m[5]  = {0, 0, 128, 0, 128};
    const int c0m[5]  = {0, 128, 128, 384, 384};
    const int wofm[5] = {PK2_J0, PK2_J1, PK2_J1, PK2_J2, PK2_J2};

    __shared__ ushort smC[17408];           // staging 10240 | epi 17408 (aliased)
    ushort* Al = smC;
    ushort* Bl = smC + 5120;
    int wg = xcd_swz();
    int y = wg % 5, rtile = wg / 5;
    int Kcp = kcpm[y], off = offm[y], o0 = o0m[y];
    int c0X = c0m[y] + o0;
    int r0g = rowBase + rtile * 128;
    int slot = r0g / SLOTROWS;
    const ushort* Wt = Wpack + slot * PK2_SLOT + wofm[y] + (size_t)o0 * Kcp;
    const float*  bp = bpack + slot * CT;
    int p0 = rtile * 128;

    int t = threadIdx.x, lane = t & 63, w = t >> 6;
    int r0 = (w >> 1) * 64, c0w = (w & 1) * 64;

    int row_a = t >> 2, seg = t & 3;
    int rg0 = r0g + row_a, rg1 = rg0 + 64;
    int rr0 = rg0 - slot * SLOTROWS, rr1 = rg1 - slot * SLOTROWS;
    size_t wb0 = (size_t)(rr0 / LO) * GROW + (off + rr0 % LO) * LPAD;
    size_t wb1 = (size_t)(rr1 / LO) * GROW + (off + rr1 % LO) * LPAD;

    f4v acc[4][4];
    #pragma unroll
    for (int m = 0; m < 4; ++m)
        #pragma unroll
        for (int n = 0; n < 4; ++n)
            acc[m][n] = (f4v){0.f, 0.f, 0.f, 0.f};

    int nkt = Kcp >> 5;
    for (int kt = 0; kt < nkt; ++kt) {
        int k0 = kt << 5;
        __syncthreads();
        *(s8v*)&Al[row_a * 40 + seg * 8]        = *(const s8v*)&Gb[wb0 + k0 + seg * 8];
        *(s8v*)&Al[(row_a + 64) * 40 + seg * 8] = *(const s8v*)&Gb[wb1 + k0 + seg * 8];
        *(s8v*)&Bl[row_a * 40 + seg * 8]        = *(const s8v*)&Wt[(size_t)row_a * Kcp + k0 + seg * 8];
        *(s8v*)&Bl[(row_a + 64) * 40 + seg * 8] = *(const s8v*)&Wt[(size_t)(row_a + 64) * Kcp + k0 + seg * 8];
        __syncthreads();
        s8v a[4], b[4];
        #pragma unroll
        for (int m = 0; m < 4; ++m)
            a[m] = *(const s8v*)&Al[(r0 + m * 16 + (lane & 15)) * 40 + (lane >> 4) * 8];
        #pragma unroll
        for (int n = 0; n < 4; ++n)
            b[n] = *(const s8v*)&Bl[(c0w + n * 16 + (lane & 15)) * 40 + (lane >> 4) * 8];
        #pragma unroll
        for (int m = 0; m < 4; ++m)
            #pragma unroll
            for (int n = 0; n < 4; ++n)
                acc[m][n] = __builtin_amdgcn_mfma_f32_16x16x32_bf16(a[m], b[n], acc[m][n], 0, 0, 0);
    }

    int cl = lane & 15, rq = lane >> 4;
    __syncthreads();
    #pragma unroll
    for (int m = 0; m < 4; ++m)
        #pragma unroll
        for (int n = 0; n < 4; ++n) {
            int ocr = c0w + n * 16 + cl;
            float bv = bp[c0X + ocr];
            #pragma unroll
            for (int j = 0; j < 4; ++j)
                smC[(r0 + m * 16 + rq * 4 + j) * 136 + ocr] = f2b(fmaxf(acc[m][n][j] + bv, 0.f));
        }
    __syncthreads();
    int ci = t & 15;
    #pragma unroll
    for (int it = 0; it < 8; ++it) {
        int row = (t >> 4) + it * 16;
        *(s8v*)&Xb[(size_t)(p0 + row) * CT + c0X + ci * 8] = *(const s8v*)&smC[row * 136 + ci * 8];
    }
}

// ---------------- MLP stage A: bf16 MFMA GEMM, BK=64, XCD-swizzled ----------------
__global__ __launch_bounds__(256) void k_mgemmA(
    const ushort* __restrict__ Xin,
    const ushort* __restrict__ Wbase, const float* __restrict__ bbase,
    ushort* __restrict__ Yb, int rowBase)
{
    __shared__ ushort smA[18432];          // staging 2*9216 | epi 17408 (aliased)
    ushort* Al = smA;
    ushort* Bl = smA + 9216;
    int t = threadIdx.x;
    int wg = xcd_swz();
    int o0 = (wg & 3) * 128;
    int p0 = (wg >> 2) * 128;
    int g0 = rowBase + p0;
    int fam = (g0 < SLOTROWS) ? 0 : 1;
    const ushort* Wb = Wbase + (size_t)fam * WMLP_FAM;
    const float*  bp = bbase + fam * BMLP_FAM;
    int lane = t & 63, w = t >> 6;
    int r0 = (w >> 1) * 64, c0 = (w & 1) * 64;

    f4v acc[4][4];
    #pragma unroll
    for (int m = 0; m < 4; ++m)
        #pragma unroll
        for (int n = 0; n < 4; ++n)
            acc[m][n] = (f4v){0.f, 0.f, 0.f, 0.f};

    for (int kt = 0; kt < CT / 64; ++kt) {
        int k0 = kt << 6;
        __syncthreads();
        #pragma unroll
        for (int it = 0; it < 4; ++it) {
            int idx = t + it * 256;
            int row = idx >> 3, sg = idx & 7;
            *(s8v*)&Al[row * 72 + sg * 8] = *(const s8v*)&Xin[(size_t)(p0 + row) * CT + k0 + sg * 8];
            *(s8v*)&Bl[row * 72 + sg * 8] = *(const s8v*)&Wb[(size_t)(o0 + row) * CT + k0 + sg * 8];
        }
        __syncthreads();
        #pragma unroll
        for (int ks = 0; ks < 2; ++ks) {
            int kc = ks * 32 + (lane >> 4) * 8;
            s8v a[4], b[4];
            #pragma unroll
            for (int m = 0; m < 4; ++m)
                a[m] = *(const s8v*)&Al[(r0 + m * 16 + (lane & 15)) * 72 + kc];
            #pragma unroll
            for (int n = 0; n < 4; ++n)
                b[n] = *(const s8v*)&Bl[(c0 + n * 16 + (lane & 15)) * 72 + kc];
            #pragma unroll
            for (int m = 0; m < 4; ++m)
                #pragma unroll
                for (int n = 0; n < 4; ++n)
                    acc[m][n] = __builtin_amdgcn_mfma_f32_16x16x32_bf16(a[m], b[n], acc[m][n], 0, 0, 0);
        }
    }

    int cl = lane & 15, rq = lane >> 4;
    __syncthreads();
    #pragma unroll
    for (int m = 0; m < 4; ++m)
        #pragma unroll
        for (int n = 0; n < 4; ++n) {
            int ocr = c0 + n * 16 + cl;
            float bv = bp[o0 + ocr];
            #pragma unroll
            for (int j = 0; j < 4; ++j)
                smA[(r0 + m * 16 + rq * 4 + j) * 136 + ocr] = f2b(fmaxf(acc[m][n][j] + bv, 0.f));
        }
    __syncthreads();
    int ci = t & 15;
    #pragma unroll
    for (int it = 0; it < 8; ++it) {
        int row = (t >> 4) + it * 16;
        *(s8v*)&Yb[(size_t)(p0 + row) * H1 + o0 + ci * 8] = *(const s8v*)&smA[row * 136 + ci * 8];
    }
}

// ---------------- MLP stage B fused with masked max-pool, XCD-swizzled ----------------
__global__ __launch_bounds__(256) void k_mgemmB(
    const ushort* __restrict__ Yin,
    const ushort* __restrict__ Wbase, const float* __restrict__ bbase,
    const int* __restrict__ pep_x, int* __restrict__ poolI, int rowBase)
{
    __shared__ float zbuf[128 * 129];      // 66048 B; staging aliased at front
    __shared__ int mvalid[128];
    ushort* Al = (ushort*)zbuf;
    ushort* Bl = Al + 9216;
    int t = threadIdx.x;
    int wg = xcd_swz();
    int o0 = (wg & 1) * 128;
    int p0 = (wg >> 1) * 128;
    int g0 = rowBase + p0;
    int slot = g0 / SLOTROWS;
    int gs0 = g0 - slot * SLOTROWS;
    int fam = (slot == 0) ? 0 : 1;
    const ushort* Wb = Wbase + (size_t)fam * WMLP_FAM + WMLP_B;
    const float*  bp = bbase + fam * BMLP_FAM + BMLP_B;
    int lane = t & 63, w = t >> 6;
    int r0 = (w >> 1) * 64, c0 = (w & 1) * 64;

    f4v acc[4][4];
    #pragma unroll
    for (int m = 0; m < 4; ++m)
        #pragma unroll
        for (int n = 0; n < 4; ++n)
            acc[m][n] = (f4v){0.f, 0.f, 0.f, 0.f};

    for (int kt = 0; kt < H1 / 64; ++kt) {
        int k0 = kt << 6;
        __syncthreads();
        #pragma unroll
        for (int it = 0; it < 4; ++it) {
            int idx = t + it * 256;
            int row = idx >> 3, sg = idx & 7;
            *(s8v*)&Al[row * 72 + sg * 8] = *(const s8v*)&Yin[(size_t)(p0 + row) * H1 + k0 + sg * 8];
            *(s8v*)&Bl[row * 72 + sg * 8] = *(const s8v*)&Wb[(size_t)(o0 + row) * H1 + k0 + sg * 8];
        }
        __syncthreads();
        #pragma unroll
        for (int ks = 0; ks < 2; ++ks) {
            int kc = ks * 32 + (lane >> 4) * 8;
            s8v a[4], b[4];
            #pragma unroll
            for (int m = 0; m < 4; ++m)
                a[m] = *(const s8v*)&Al[(r0 + m * 16 + (lane & 15)) * 72 + kc];
            #pragma unroll
            for (int n = 0; n < 4; ++n)
                b[n] = *(const s8v*)&Bl[(c0 + n * 16 + (lane & 15)) * 72 + kc];
            #pragma unroll
            for (int m = 0; m < 4; ++m)
                #pragma unroll
                for (int n = 0; n < 4; ++n)
                    acc[m][n] = __builtin_amdgcn_mfma_f32_16x16x32_bf16(a[m], b[n], acc[m][n], 0, 0, 0);
        }
    }

    int cl = lane & 15, rq = lane >> 4;
    __syncthreads();
    if (t < 128) {
        int gs = gs0 + t;
        int n = gs / LO, i = gs - n * LO;
        mvalid[t] = (pep_x[n * LP + 3 + i] != 0) ? 1 : 0;
    }
    #pragma unroll
    for (int m = 0; m < 4; ++m)
        #pragma unroll
        for (int n = 0; n < 4; ++n) {
            int ocr = c0 + n * 16 + cl;
            float bv = bp[o0 + ocr];
            #pragma unroll
            for (int j = 0; j < 4; ++j)
                zbuf[(r0 + m * 16 + rq * 4 + j) * 129 + ocr] = fmaxf(acc[m][n][j] + bv, 0.f);
        }
    __syncthreads();

    int col = t & 127, half = t >> 7;
    int colg = o0 + col;
    int rs = half * 64;
    int gs = gs0 + rs;
    int n = gs / LO, i = gs - n * LO;
    float cur = -1.f;
    for (int r = rs; r < rs + 64; ++r) {
        if (mvalid[r]) cur = fmaxf(cur, zbuf[r * 129 + col]);
        if (++i == LO) {
            if (cur >= 0.f)
                atomicMax(&poolI[n * (3 * H2) + slot * H2 + colg], __float_as_int(cur));
            cur = -1.f; ++n; i = 0;
        }
    }
    if (cur >= 0.f)
        atomicMax(&poolI[n * (3 * H2) + slot * H2 + colg], __float_as_int(cur));
}

// ---------------- attention head per sample ----------------
__global__ __launch_bounds__(256) void k_poolhead(
    const float* __restrict__ pool,
    const float* __restrict__ w_att1, const float* __restrict__ b_att1,
    const float* __restrict__ w_att2, const float* __restrict__ b_att2,
    const float* __restrict__ w_out, const float* __restrict__ b_out,
    float* __restrict__ a_out, float* __restrict__ s2_out)
{
    int n = blockIdx.x, c = threadIdx.x;
    __shared__ float feat_s[H2];
    __shared__ float red[7][H2];
    __shared__ float sc_s[6];

    float mx[3];
    #pragma unroll
    for (int w = 0; w < 3; ++w)
        mx[w] = pool[(size_t)n * (3 * H2) + w * H2 + c];

    float fv = (mx[0] + mx[1] + mx[2]) * (1.f / 3.f);
    feat_s[c] = fv;
    #pragma unroll
    for (int o = 0; o < 2; ++o)
        #pragma unroll
        for (int w = 0; w < 3; ++w)
            red[o * 3 + w][c] = w_out[o * H2 + c] * mx[w];
    __syncthreads();

    float hacc = 0.f;
    for (int cc = 0; cc < H2; ++cc)
        hacc = fmaf(w_att1[(size_t)c * H2 + cc], feat_s[cc], hacc);
    float h = tanhf(hacc + b_att1[c]);
    red[6][c] = h * w_att2[c];
    __syncthreads();

    for (int s = 128; s > 0; s >>= 1) {
        if (c < s) {
            #pragma unroll
            for (int jj = 0; jj < 7; ++jj) red[jj][c] += red[jj][c + s];
        }
        __syncthreads();
    }
    if (c == 0) a_out[n] = red[6][0] + b_att2[0];
    if (c < 6) {
        float x = red[c][0] + b_out[c / 3];
        sc_s[c] = 1.f / (1.f + expf(-x));
    }
    __syncthreads();
    if (c < 2) {
        float half = 0.5f * (sc_s[c * 3 + 0] + sc_s[c * 3 + 1]);
        s2_out[n * 2 + c] = fmaxf(half, sc_s[c * 3 + 2]);   // inverse==1 path
    }
}

// ---------------- bag segment softmax + weighted sum ----------------
__global__ __launch_bounds__(1024) void k_final(
    const float* __restrict__ a_in, const float* __restrict__ s2_in,
    const int* __restrict__ bags, float* __restrict__ out)
{
    __shared__ float a_s[NS], s0_s[NS], s1_s[NS];
    __shared__ int off_s[33];
    int t = threadIdx.x;
    a_s[t]  = a_in[t];
    s0_s[t] = s2_in[t * 2 + 0];
    s1_s[t] = s2_in[t * 2 + 1];
    if (t == 0) {
        off_s[0] = 0;
        for (int g = 0; g < 32; ++g) off_s[g + 1] = off_s[g] + bags[g];
    }
    __syncthreads();
    if (t < 32) {
        int st = off_s[t], en = off_s[t + 1];
        float mxv = -INFINITY;
        for (int n = st; n < en; ++n) mxv = fmaxf(mxv, a_s[n]);
        float se = 0.f;
        for (int n = st; n < en; ++n) se += expf(a_s[n] - mxv);
        float inv = 1.f / se;
        float o0 = 0.f, o1 = 0.f;
        for (int n = st; n < en; ++n) {
            float w = expf(a_s[n] - mxv) * inv;
            o0 += w * s0_s[n];
            o1 += w * s1_s[n];
        }
        out[t * 2 + 0] = fminf(fmaxf(o0, 0.f), 1.f);
        out[t * 2 + 1] = fminf(fmaxf(o1, 0.f), 1.f);
    }
}

extern "C" void kernel_launch(void* const* d_in, const int* in_sizes, int n_in,
                              void* d_out, int out_size, void* d_ws, size_t ws_size,
                              hipStream_t stream) {
    const int* pep_x = (const int*)d_in[0];
    const int* mhc_x = (const int*)d_in[1];
    const int* bags  = (const int*)d_in[4];

    char* wsb = (char*)d_ws;
    float*  pool   = (float*) (wsb + 0);          // 3,145,728 (stored as int bits)
    int*    poolI  = (int*)   (wsb + 0);
    float*  a_buf  = (float*) (wsb + 3145728);
    float*  s2_buf = (float*) (wsb + 3149824);
    ushort* Wpack  = (ushort*)(wsb + 3158016);
    float*  bpack  = (float*) (wsb + 4042752);
    ushort* Wmlp   = (ushort*)(wsb + 4050432);
    float*  bmlp   = (float*) (wsb + 5885440);
    ushort* Gb     = (ushort*)(wsb + 5891584);
    const size_t XB_B = 8103552;

    size_t fullNeed = XB_B + (size_t)ALLROWS * (1280 + 1024);
    int chunkSlots = (fullNeed <= ws_size) ? 3 : 1;
    int RC = chunkSlots * SLOTROWS;
    ushort* Xb = (ushort*)(wsb + XB_B);                       // RC*640 bf16
    ushort* Yb = (ushort*)((char*)Xb + (size_t)RC * 1280);    // RC*512 bf16

    PrepArgs pa;
    pa.pep_x = pep_x; pa.mhc_x = mhc_x;
    pa.emb_pep = (const float*)d_in[6];
    pa.emb_mhc = (const float*)d_in[7];
    for (int j = 0; j < 3; ++j) {
        pa.cw[0][j]  = (const float*)d_in[8 + 4 * j];
        pa.cb[0][j]  = (const float*)d_in[9 + 4 * j];
        pa.cg[0][j]  = (const float*)d_in[10 + 4 * j];
        pa.cbe[0][j] = (const float*)d_in[11 + 4 * j];
        pa.cw[1][j]  = (const float*)d_in[20 + 4 * j];
        pa.cb[1][j]  = (const float*)d_in[21 + 4 * j];
        pa.cg[1][j]  = (const float*)d_in[22 + 4 * j];
        pa.cbe[1][j] = (const float*)d_in[23 + 4 * j];
    }
    for (int task = 0; task < 4; ++task) {
        int base = 32 + task * 4;
        pa.mw[task]  = (const float*)d_in[base + 0];
        pa.mb[task]  = (const float*)d_in[base + 1];
        pa.mg[task]  = (const float*)d_in[base + 2];
        pa.mbe[task] = (const float*)d_in[base + 3];
    }
    pa.Gb = Gb; pa.Wpack = Wpack; pa.bpack = bpack; pa.Wmlp = Wmlp; pa.bmlp = bmlp;
    pa.poolI = poolI;

    k_prep<<<dim3(NS + 144 + 112 + 96), dim3(256), 0, stream>>>(pa);

    for (int rowBase = 0; rowBase < ALLROWS; rowBase += RC) {
        int nRB = RC / 128;
        k_cmfma<<<dim3(5, nRB), dim3(256), 0, stream>>>(Gb, Wpack, bpack, Xb, rowBase);
        k_mgemmA<<<dim3(H1 / 128, nRB), dim3(256), 0, stream>>>(Xb, Wmlp, bmlp, Yb, rowBase);
        k_mgemmB<<<dim3(H2 / 128, nRB), dim3(256), 0, stream>>>(Yb, Wmlp, bmlp, pep_x, poolI, rowBase);
    }

    k_poolhead<<<dim3(NS), dim3(256), 0, stream>>>(
        pool,
        (const float*)d_in[48], (const float*)d_in[49], (const float*)d_in[50], (const float*)d_in[51],
        (const float*)d_in[52], (const float*)d_in[53],
        a_buf, s2_buf);

    k_final<<<dim3(1), dim3(1024), 0, stream>>>(a_buf, s2_buf, bags, (float*)d_out);
}